// Round 1
// baseline (2089.718 us; speedup 1.0000x reference)
//
#include <hip/hip_runtime.h>
#include <hip/hip_bf16.h>

// Problem constants
#define BB 8
#define NN 2048
#define DD 512
#define CFF 128
#define MT (BB*NN)   // 16384

// ---------------- generic tiled f32 GEMM ----------------
// C[M,N] = epi(alpha * A[M,K] @ op(B)), op(B) = B[K,N] (BT=false) or B[N,K]^T (BT=true)
// Tile 128x128, BK=16, thread tile 8x8 (split 4+4 across halves), 256 threads.
// EPI: 0 = alpha*acc ; 1 = leakyrelu(acc + bias[n], 0.1) ; 2 = max(alpha*acc - tvec[b*M+row], 0)

template<bool BT, int EPI>
__global__ __launch_bounds__(256) void gemm_kernel(
    const float* __restrict__ A, const float* __restrict__ B, float* __restrict__ C,
    int M, int N, int K, int lda, int ldb, int ldc,
    long sA, long sB, long sC, float alpha,
    const float* __restrict__ bias, const float* __restrict__ tvec)
{
    A += (long)blockIdx.z * sA;
    B += (long)blockIdx.z * sB;
    C += (long)blockIdx.z * sC;

    __shared__ float As[16][132];
    __shared__ float Bs[16][132];

    const int tid = threadIdx.x;
    const int tx = tid & 15;      // col group 0..15
    const int ty = tid >> 4;      // row group 0..15
    const int row0 = blockIdx.y * 128;
    const int col0 = blockIdx.x * 128;

    float acc[8][8];
#pragma unroll
    for (int i = 0; i < 8; ++i)
#pragma unroll
        for (int j = 0; j < 8; ++j) acc[i][j] = 0.f;

    for (int k0 = 0; k0 < K; k0 += 16) {
        // ---- load A tile: rows row0..+127, cols k0..+15 (transposed into As[k][m]) ----
#pragma unroll
        for (int i = 0; i < 2; ++i) {
            int e = tid + i * 256;          // 0..511
            int r = e >> 2;                 // 0..127
            int c = (e & 3) << 2;           // 0,4,8,12
            const float4 v = *reinterpret_cast<const float4*>(A + (long)(row0 + r) * lda + k0 + c);
            As[c + 0][r] = v.x; As[c + 1][r] = v.y; As[c + 2][r] = v.z; As[c + 3][r] = v.w;
        }
        if (!BT) {
            // B[K,N]: tile rows k0..+15, cols col0..+127
#pragma unroll
            for (int i = 0; i < 2; ++i) {
                int e = tid + i * 256;      // 0..511
                int r = e >> 5;             // 0..15  (k)
                int c = (e & 31) << 2;      // 0..124 (n)
                const float4 v = *reinterpret_cast<const float4*>(B + (long)(k0 + r) * ldb + col0 + c);
                *reinterpret_cast<float4*>(&Bs[r][c]) = v;
            }
        } else {
            // B[N,K]: tile rows(n) col0..+127, cols(k) k0..+15 (transposed into Bs[k][n])
#pragma unroll
            for (int i = 0; i < 2; ++i) {
                int e = tid + i * 256;
                int r = e >> 2;             // 0..127 (n)
                int c = (e & 3) << 2;       // 0,4,8,12 (k)
                const float4 v = *reinterpret_cast<const float4*>(B + (long)(col0 + r) * ldb + k0 + c);
                Bs[c + 0][r] = v.x; Bs[c + 1][r] = v.y; Bs[c + 2][r] = v.z; Bs[c + 3][r] = v.w;
            }
        }
        __syncthreads();

#pragma unroll
        for (int kk = 0; kk < 16; ++kk) {
            float4 a0 = *reinterpret_cast<const float4*>(&As[kk][ty * 4]);
            float4 a1 = *reinterpret_cast<const float4*>(&As[kk][64 + ty * 4]);
            float4 b0 = *reinterpret_cast<const float4*>(&Bs[kk][tx * 4]);
            float4 b1 = *reinterpret_cast<const float4*>(&Bs[kk][64 + tx * 4]);
            float av[8] = {a0.x, a0.y, a0.z, a0.w, a1.x, a1.y, a1.z, a1.w};
            float bv[8] = {b0.x, b0.y, b0.z, b0.w, b1.x, b1.y, b1.z, b1.w};
#pragma unroll
            for (int i = 0; i < 8; ++i)
#pragma unroll
                for (int j = 0; j < 8; ++j)
                    acc[i][j] = fmaf(av[i], bv[j], acc[i][j]);
        }
        __syncthreads();
    }

    // ---- epilogue ----
#pragma unroll
    for (int i = 0; i < 8; ++i) {
        int r = row0 + ((i < 4) ? (ty * 4 + i) : (64 + ty * 4 + (i - 4)));
        float tv = 0.f;
        if (EPI == 2) tv = tvec[(long)blockIdx.z * M + r];
#pragma unroll
        for (int half = 0; half < 2; ++half) {
            int c = col0 + (half ? 64 : 0) + tx * 4;
            float4 o;
            float* po = reinterpret_cast<float*>(&o);
#pragma unroll
            for (int j = 0; j < 4; ++j) {
                float v = acc[i][half * 4 + j];
                if (EPI == 0) {
                    v = v * alpha;
                } else if (EPI == 1) {
                    v = v + bias[c + j];
                    v = (v >= 0.f) ? v : 0.1f * v;
                } else {
                    v = fmaxf(v * alpha - tv, 0.f);
                }
                po[j] = v;
            }
            *reinterpret_cast<float4*>(C + (long)r * ldc + c) = o;
        }
    }
}

// ---------------- reductions / elementwise ----------------
__device__ __forceinline__ float waveReduceMax(float v) {
#pragma unroll
    for (int o = 32; o; o >>= 1) v = fmaxf(v, __shfl_down(v, o));
    return v;
}
__device__ __forceinline__ float waveReduceSum(float v) {
#pragma unroll
    for (int o = 32; o; o >>= 1) v += __shfl_down(v, o);
    return v;
}

// softmax over rows of 2048, in place
__global__ __launch_bounds__(256) void softmax_kernel(float* __restrict__ S)
{
    __shared__ float red[4];
    __shared__ float fin;
    long row = blockIdx.x;
    float* p = S + row * (long)NN;
    int t = threadIdx.x;

    float4 v0 = *reinterpret_cast<float4*>(p + t * 8);
    float4 v1 = *reinterpret_cast<float4*>(p + t * 8 + 4);

    float m = fmaxf(fmaxf(fmaxf(v0.x, v0.y), fmaxf(v0.z, v0.w)),
                    fmaxf(fmaxf(v1.x, v1.y), fmaxf(v1.z, v1.w)));
    m = waveReduceMax(m);
    if ((t & 63) == 0) red[t >> 6] = m;
    __syncthreads();
    if (t == 0) fin = fmaxf(fmaxf(red[0], red[1]), fmaxf(red[2], red[3]));
    __syncthreads();
    m = fin;

    float e[8];
    e[0] = __expf(v0.x - m); e[1] = __expf(v0.y - m); e[2] = __expf(v0.z - m); e[3] = __expf(v0.w - m);
    e[4] = __expf(v1.x - m); e[5] = __expf(v1.y - m); e[6] = __expf(v1.z - m); e[7] = __expf(v1.w - m);
    float s = ((e[0] + e[1]) + (e[2] + e[3])) + ((e[4] + e[5]) + (e[6] + e[7]));
    s = waveReduceSum(s);
    __syncthreads();
    if ((t & 63) == 0) red[t >> 6] = s;
    __syncthreads();
    if (t == 0) fin = (red[0] + red[1]) + (red[2] + red[3]);
    __syncthreads();
    float inv = 1.0f / fin;

    v0.x = e[0] * inv; v0.y = e[1] * inv; v0.z = e[2] * inv; v0.w = e[3] * inv;
    v1.x = e[4] * inv; v1.y = e[5] * inv; v1.z = e[6] * inv; v1.w = e[7] * inv;
    *reinterpret_cast<float4*>(p + t * 8) = v0;
    *reinterpret_cast<float4*>(p + t * 8 + 4) = v1;
}

// row sums of surv (rows of 2048)
__global__ __launch_bounds__(256) void rowsum_kernel(const float* __restrict__ S, float* __restrict__ sums)
{
    __shared__ float red[4];
    long row = blockIdx.x;
    const float* p = S + row * (long)NN;
    int t = threadIdx.x;
    float4 v0 = *reinterpret_cast<const float4*>(p + t * 8);
    float4 v1 = *reinterpret_cast<const float4*>(p + t * 8 + 4);
    float s = ((v0.x + v0.y) + (v0.z + v0.w)) + ((v1.x + v1.y) + (v1.z + v1.w));
    s = waveReduceSum(s);
    if ((t & 63) == 0) red[t >> 6] = s;
    __syncthreads();
    if (t == 0) sums[row] = (red[0] + red[1]) + (red[2] + red[3]);
}

// A = clip(surv / (sum+1e-9), 0, 1) in place
__global__ __launch_bounds__(256) void norm_kernel(float* __restrict__ S, const float* __restrict__ sums)
{
    long i = (long)blockIdx.x * 256 + threadIdx.x;
    long base = i * 4;
    long row = base >> 11;   // NN = 2048
    float inv = 1.0f / (sums[row] + 1e-9f);
    float4 v = *reinterpret_cast<float4*>(S + base);
    v.x = fminf(v.x * inv, 1.0f);
    v.y = fminf(v.y * inv, 1.0f);
    v.z = fminf(v.z * inv, 1.0f);
    v.w = fminf(v.w * inv, 1.0f);
    *reinterpret_cast<float4*>(S + base) = v;
}

// thresh[row] = dot(h[row, 0:128], W2) + b2
__global__ __launch_bounds__(64) void thresh_kernel(const float* __restrict__ h,
                                                    const float* __restrict__ W2,
                                                    const float* __restrict__ b2,
                                                    float* __restrict__ th)
{
    int row = blockIdx.x;
    int t = threadIdx.x;
    const float* hp = h + (long)row * CFF;
    float v = hp[t] * W2[t] + hp[t + 64] * W2[t + 64];
    v = waveReduceSum(v);
    if (t == 0) th[row] = v + b2[0];
}

// ---------------- host-side dispatch ----------------
static void launch_gemm(hipStream_t s, bool BT, int epi,
                        const float* A, const float* B, float* C,
                        int M, int N, int K, int lda, int ldb, int ldc,
                        long sA, long sB, long sC, int batch, float alpha,
                        const float* bias, const float* tvec)
{
    dim3 g(N / 128, M / 128, batch), b(256, 1, 1);
    if (!BT) {
        if (epi == 0)      gemm_kernel<false, 0><<<g, b, 0, s>>>(A, B, C, M, N, K, lda, ldb, ldc, sA, sB, sC, alpha, bias, tvec);
        else if (epi == 1) gemm_kernel<false, 1><<<g, b, 0, s>>>(A, B, C, M, N, K, lda, ldb, ldc, sA, sB, sC, alpha, bias, tvec);
        else               gemm_kernel<false, 2><<<g, b, 0, s>>>(A, B, C, M, N, K, lda, ldb, ldc, sA, sB, sC, alpha, bias, tvec);
    } else {
        if (epi == 0)      gemm_kernel<true, 0><<<g, b, 0, s>>>(A, B, C, M, N, K, lda, ldb, ldc, sA, sB, sC, alpha, bias, tvec);
        else if (epi == 1) gemm_kernel<true, 1><<<g, b, 0, s>>>(A, B, C, M, N, K, lda, ldb, ldc, sA, sB, sC, alpha, bias, tvec);
        else               gemm_kernel<true, 2><<<g, b, 0, s>>>(A, B, C, M, N, K, lda, ldb, ldc, sA, sB, sC, alpha, bias, tvec);
    }
}

extern "C" void kernel_launch(void* const* d_in, const int* in_sizes, int n_in,
                              void* d_out, int out_size, void* d_ws, size_t ws_size,
                              hipStream_t stream)
{
    const float* X   = (const float*)d_in[0];
    const float* Wq1 = (const float*)d_in[1];
    const float* Wk1 = (const float*)d_in[2];
    const float* Wv1 = (const float*)d_in[3];
    const float* Wo1 = (const float*)d_in[4];
    const float* Wq2 = (const float*)d_in[5];
    const float* Wk2 = (const float*)d_in[6];
    const float* W1  = (const float*)d_in[7];
    const float* b1  = (const float*)d_in[8];
    const float* W2  = (const float*)d_in[9];
    const float* b2  = (const float*)d_in[10];

    float* out = (float*)d_out;          // [B,N,N] = 8*2048*2048
    float* ws  = (float*)d_ws;

    const float scale = 0.044194173824159216f;  // 1/sqrt(512)
    const long SLOT = (long)MT * DD;            // 8,388,608 floats

    // 3-slot reuse plan (total ws: 3*SLOT + 16384*128 + 2*16384 floats ~ 109 MB)
    float* q1 = ws;                 // slot0: q1 -> att
    float* k1 = ws + SLOT;          // slot1: k1 -> attout -> q2
    float* v1 = ws + 2 * SLOT;      // slot2: v1 -> k2
    float* ao = k1;                 // attout reuses slot1 (k1 dead after s1)
    float* att = q1;                // att reuses slot0 (q1 dead after s1)
    float* q2 = k1;                 // reuses slot1 (ao dead after att)
    float* k2 = v1;                 // reuses slot2 (v1 dead after PV)
    float* h      = ws + 3 * SLOT;                  // [16384,128]
    float* thresh = h + (long)MT * CFF;             // [16384]
    float* sums   = thresh + MT;                    // [16384]

    // 1) q1 = X@Wq1 ; k1 = X@Wk1 ; v1 = X@Wv1
    launch_gemm(stream, false, 0, X, Wq1, q1, MT, DD, DD, DD, DD, DD, 0, 0, 0, 1, 1.f, nullptr, nullptr);
    launch_gemm(stream, false, 0, X, Wk1, k1, MT, DD, DD, DD, DD, DD, 0, 0, 0, 1, 1.f, nullptr, nullptr);
    launch_gemm(stream, false, 0, X, Wv1, v1, MT, DD, DD, DD, DD, DD, 0, 0, 0, 1, 1.f, nullptr, nullptr);

    // 2) s1 = scale * q1 @ k1^T  (batched, into d_out)
    launch_gemm(stream, true, 0, q1, k1, out, NN, NN, DD, DD, DD, NN,
                (long)NN * DD, (long)NN * DD, (long)NN * NN, BB, scale, nullptr, nullptr);

    // 3) p1 = softmax(s1) in place
    softmax_kernel<<<dim3(MT), dim3(256), 0, stream>>>(out);

    // 4) attout = p1 @ v1 (batched)   [NOTE: k1 becomes dead; ao aliases k1]
    launch_gemm(stream, false, 0, out, v1, ao, NN, DD, NN, NN, DD, DD,
                (long)NN * NN, (long)NN * DD, (long)NN * DD, BB, 1.f, nullptr, nullptr);

    // 5) att = attout @ Wo1
    launch_gemm(stream, false, 0, ao, Wo1, att, MT, DD, DD, DD, DD, DD, 0, 0, 0, 1, 1.f, nullptr, nullptr);

    // 6) q2 = att@Wq2 ; k2 = att@Wk2
    launch_gemm(stream, false, 0, att, Wq2, q2, MT, DD, DD, DD, DD, DD, 0, 0, 0, 1, 1.f, nullptr, nullptr);
    launch_gemm(stream, false, 0, att, Wk2, k2, MT, DD, DD, DD, DD, DD, 0, 0, 0, 1, 1.f, nullptr, nullptr);

    // 7) h = leakyrelu(att@W1 + b1)
    launch_gemm(stream, false, 1, att, W1, h, MT, CFF, DD, DD, CFF, CFF, 0, 0, 0, 1, 1.f, b1, nullptr);

    // 8) thresh = h@W2 + b2
    thresh_kernel<<<dim3(MT), dim3(64), 0, stream>>>(h, W2, b2, thresh);

    // 9) surv = max(scale * q2@k2^T - thresh[row], 0)  (batched, into d_out)
    launch_gemm(stream, true, 2, q2, k2, out, NN, NN, DD, DD, DD, NN,
                (long)NN * DD, (long)NN * DD, (long)NN * NN, BB, scale, nullptr, thresh);

    // 10) row sums of surv
    rowsum_kernel<<<dim3(MT), dim3(256), 0, stream>>>(out, sums);

    // 11) A = clip(surv/(sum+1e-9), 0, 1)
    norm_kernel<<<dim3(out_size / 1024), dim3(256), 0, stream>>>(out, sums);
}

// Round 2
// 900.033 us; speedup vs baseline: 2.3218x; 2.3218x over previous
//
#include <hip/hip_runtime.h>
#include <hip/hip_bf16.h>

// Problem constants
#define BB 8
#define NN 2048
#define DD 512
#define CFF 128
#define MT (BB*NN)   // 16384

typedef _Float16 half_t;
typedef __attribute__((ext_vector_type(8))) _Float16 half8;
typedef __attribute__((ext_vector_type(4))) float floatx4;
typedef __attribute__((ext_vector_type(4))) unsigned int uint4v;

#define MFMA16(a,b,c) __builtin_amdgcn_mfma_f32_16x16x32_f16((a),(b),(c),0,0,0)

// ============================================================================
// fp16-split MFMA GEMM:  C = epi( alpha * (Ahi+Alo) @ (Bhi+Blo)^T )
// A: [M,K] row-major (element stride lda), B: [N,K] row-major (ldb) — both
// pre-split into hi/lo f16. Computes hi*hi + lo*hi + hi*lo (f32-class accuracy).
// Tile 128x128, BK=32, 4 waves of 64x64 (4x4 frags of 16x16x32 MFMA).
// LDS: 16B-chunk XOR swizzle (chunk ^= row&3) -> conflict-light reads+writes.
// EPI: 0 = alpha*acc -> Cf ; 1 = hi/lo split -> Chi/Clo ;
//      2 = leakyrelu(acc + bias[col]) -> Cf ; 3 = max(alpha*acc - tvec[row],0) -> Cf
// ============================================================================
template<int EPI>
__global__ __launch_bounds__(256) void gemm_f16s(
    const half_t* __restrict__ Ahi, const half_t* __restrict__ Alo, long lda, long sA,
    const half_t* __restrict__ Bhi, const half_t* __restrict__ Blo, long ldb, long sB,
    float* __restrict__ Cf, half_t* __restrict__ Chi, half_t* __restrict__ Clo, long ldc, long sC,
    int K, float alpha, const float* __restrict__ bias, const float* __restrict__ tvec)
{
    const int tid = threadIdx.x;
    const int row0 = blockIdx.y * 128, col0 = blockIdx.x * 128;
    const long z = blockIdx.z;
    const half_t* pAh = Ahi + z * sA + (long)row0 * lda;
    const half_t* pAl = Alo + z * sA + (long)row0 * lda;
    const half_t* pBh = Bhi + z * sB + (long)col0 * ldb;
    const half_t* pBl = Blo + z * sB + (long)col0 * ldb;

    __shared__ half_t lds[2][4][4096];   // [buf][Ah,Al,Bh,Bl][128*32]

    const int l  = tid & 63;
    const int w  = tid >> 6;
    const int wr = w >> 1, wc = w & 1;
    const int Rw = wr * 64, Cw = wc * 64;
    const int rl = l & 15, kc = l >> 4;        // frag row/col, k-chunk
    const int swz = (kc ^ (rl & 3)) * 8;       // swizzled k-offset (elems)

    floatx4 acc[4][4];
#pragma unroll
    for (int m = 0; m < 4; ++m)
#pragma unroll
        for (int n = 0; n < 4; ++n) acc[m][n] = (floatx4){0.f, 0.f, 0.f, 0.f};

    // staging slots: s in {tid, tid+256}; row = s>>2, 16B-chunk c = s&3
    const int r0s = tid >> 2,         c0s = tid & 3;
    const int r1s = (tid + 256) >> 2, c1s = tid & 3;   // (tid+256)&3 == tid&3
    const int off0 = r0s * 32 + ((c0s ^ (r0s & 3)) * 8);
    const int off1 = r1s * 32 + ((c1s ^ (r1s & 3)) * 8);

    auto stage = [&](int buf, int k0) {
        long ga0 = (long)r0s * lda + k0 + c0s * 8;
        long gb0 = (long)r0s * ldb + k0 + c0s * 8;
        long ga1 = (long)r1s * lda + k0 + c1s * 8;
        long gb1 = (long)r1s * ldb + k0 + c1s * 8;
        uint4v a0 = *(const uint4v*)(pAh + ga0);
        uint4v a1 = *(const uint4v*)(pAl + ga0);
        uint4v b0 = *(const uint4v*)(pBh + gb0);
        uint4v b1 = *(const uint4v*)(pBl + gb0);
        uint4v a2 = *(const uint4v*)(pAh + ga1);
        uint4v a3 = *(const uint4v*)(pAl + ga1);
        uint4v b2 = *(const uint4v*)(pBh + gb1);
        uint4v b3 = *(const uint4v*)(pBl + gb1);
        *(uint4v*)&lds[buf][0][off0] = a0;
        *(uint4v*)&lds[buf][1][off0] = a1;
        *(uint4v*)&lds[buf][2][off0] = b0;
        *(uint4v*)&lds[buf][3][off0] = b1;
        *(uint4v*)&lds[buf][0][off1] = a2;
        *(uint4v*)&lds[buf][1][off1] = a3;
        *(uint4v*)&lds[buf][2][off1] = b2;
        *(uint4v*)&lds[buf][3][off1] = b3;
    };

    const int nk = K >> 5;
    stage(0, 0);
#pragma unroll 2
    for (int t = 0; t < nk; ++t) {
        __syncthreads();          // writes to buf[t&1] visible to all
        const int cur = t & 1;
        const half_t* bAh = &lds[cur][0][0];
        const half_t* bAl = &lds[cur][1][0];
        const half_t* bBh = &lds[cur][2][0];
        const half_t* bBl = &lds[cur][3][0];
        half8 af[4][2], bf[4][2];
#pragma unroll
        for (int m = 0; m < 4; ++m) {
            int off = (Rw + m * 16 + rl) * 32 + swz;
            af[m][0] = *(const half8*)(bAh + off);
            af[m][1] = *(const half8*)(bAl + off);
        }
#pragma unroll
        for (int n = 0; n < 4; ++n) {
            int off = (Cw + n * 16 + rl) * 32 + swz;
            bf[n][0] = *(const half8*)(bBh + off);
            bf[n][1] = *(const half8*)(bBl + off);
        }
#pragma unroll
        for (int m = 0; m < 4; ++m)
#pragma unroll
            for (int n = 0; n < 4; ++n) {
                acc[m][n] = MFMA16(af[m][0], bf[n][0], acc[m][n]);
                acc[m][n] = MFMA16(af[m][1], bf[n][0], acc[m][n]);
                acc[m][n] = MFMA16(af[m][0], bf[n][1], acc[m][n]);
            }
        if (t + 1 < nk) stage((t + 1) & 1, (t + 1) << 5);  // other buffer: no barrier needed
    }

    // epilogue — C/D frag: col = lane&15, row = (lane>>4)*4 + reg  [m89-verified]
    const float* tv = (EPI == 3) ? (tvec + z * NN) : tvec;
#pragma unroll
    for (int m = 0; m < 4; ++m) {
#pragma unroll
        for (int n = 0; n < 4; ++n) {
            int col = col0 + Cw + n * 16 + rl;
#pragma unroll
            for (int r = 0; r < 4; ++r) {
                int row = row0 + Rw + m * 16 + kc * 4 + r;
                float v = acc[m][n][r];
                if (EPI == 0) {
                    Cf[z * sC + (long)row * ldc + col] = v * alpha;
                } else if (EPI == 1) {
                    half_t hh = (half_t)v;
                    long o = z * sC + (long)row * ldc + col;
                    Chi[o] = hh;
                    Clo[o] = (half_t)(v - (float)hh);
                } else if (EPI == 2) {
                    v += bias[col];
                    Cf[(long)row * ldc + col] = (v >= 0.f) ? v : 0.1f * v;
                } else {
                    Cf[z * sC + (long)row * ldc + col] = fmaxf(v * alpha - tv[row], 0.f);
                }
            }
        }
    }
}

// ============================================================================
// helpers: reductions / elementwise
// ============================================================================
__device__ __forceinline__ float waveReduceMax(float v) {
#pragma unroll
    for (int o = 32; o; o >>= 1) v = fmaxf(v, __shfl_down(v, o));
    return v;
}
__device__ __forceinline__ float waveReduceSum(float v) {
#pragma unroll
    for (int o = 32; o; o >>= 1) v += __shfl_down(v, o);
    return v;
}

// softmax over rows of 2048 f32 (in d_out); writes p1 hi/lo f16 IN PLACE into
// the same row's bytes: hi at f16-offset row*4096, lo at row*4096+2048.
__global__ __launch_bounds__(256) void softmax_split_kernel(float* __restrict__ S)
{
    __shared__ float red[4];
    __shared__ float fin;
    long row = blockIdx.x;
    float* p = S + row * (long)NN;
    half_t* ph = (half_t*)p;        // hi half-row
    half_t* pl = ph + NN;           // lo half-row
    int t = threadIdx.x;

    float4 v0 = *reinterpret_cast<float4*>(p + t * 8);
    float4 v1 = *reinterpret_cast<float4*>(p + t * 8 + 4);

    float m = fmaxf(fmaxf(fmaxf(v0.x, v0.y), fmaxf(v0.z, v0.w)),
                    fmaxf(fmaxf(v1.x, v1.y), fmaxf(v1.z, v1.w)));
    m = waveReduceMax(m);
    if ((t & 63) == 0) red[t >> 6] = m;
    __syncthreads();
    if (t == 0) fin = fmaxf(fmaxf(red[0], red[1]), fmaxf(red[2], red[3]));
    __syncthreads();
    m = fin;

    float e[8];
    e[0] = __expf(v0.x - m); e[1] = __expf(v0.y - m); e[2] = __expf(v0.z - m); e[3] = __expf(v0.w - m);
    e[4] = __expf(v1.x - m); e[5] = __expf(v1.y - m); e[6] = __expf(v1.z - m); e[7] = __expf(v1.w - m);
    float s = ((e[0] + e[1]) + (e[2] + e[3])) + ((e[4] + e[5]) + (e[6] + e[7]));
    s = waveReduceSum(s);
    __syncthreads();
    if ((t & 63) == 0) red[t >> 6] = s;
    __syncthreads();
    if (t == 0) fin = (red[0] + red[1]) + (red[2] + red[3]);
    __syncthreads();
    float inv = 1.0f / fin;

    __syncthreads();   // all reads of this row's f32 done before overwriting
    half8 hv, lv;
#pragma unroll
    for (int j = 0; j < 8; ++j) {
        float pv = e[j] * inv;
        half_t hh = (half_t)pv;
        hv[j] = hh;
        lv[j] = (half_t)(pv - (float)hh);
    }
    *(half8*)(ph + t * 8) = hv;
    *(half8*)(pl + t * 8) = lv;
}

// row sums of surv (rows of 2048)
__global__ __launch_bounds__(256) void rowsum_kernel(const float* __restrict__ S, float* __restrict__ sums)
{
    __shared__ float red[4];
    long row = blockIdx.x;
    const float* p = S + row * (long)NN;
    int t = threadIdx.x;
    float4 v0 = *reinterpret_cast<const float4*>(p + t * 8);
    float4 v1 = *reinterpret_cast<const float4*>(p + t * 8 + 4);
    float s = ((v0.x + v0.y) + (v0.z + v0.w)) + ((v1.x + v1.y) + (v1.z + v1.w));
    s = waveReduceSum(s);
    if ((t & 63) == 0) red[t >> 6] = s;
    __syncthreads();
    if (t == 0) sums[row] = (red[0] + red[1]) + (red[2] + red[3]);
}

// A = clip(surv / (sum+1e-9), 0, 1) in place
__global__ __launch_bounds__(256) void norm_kernel(float* __restrict__ S, const float* __restrict__ sums)
{
    long i = (long)blockIdx.x * 256 + threadIdx.x;
    long base = i * 4;
    long row = base >> 11;   // NN = 2048
    float inv = 1.0f / (sums[row] + 1e-9f);
    float4 v = *reinterpret_cast<float4*>(S + base);
    v.x = fminf(v.x * inv, 1.0f);
    v.y = fminf(v.y * inv, 1.0f);
    v.z = fminf(v.z * inv, 1.0f);
    v.w = fminf(v.w * inv, 1.0f);
    *reinterpret_cast<float4*>(S + base) = v;
}

// thresh[row] = dot(h[row, 0:128], W2) + b2
__global__ __launch_bounds__(64) void thresh_kernel(const float* __restrict__ h,
                                                    const float* __restrict__ W2,
                                                    const float* __restrict__ b2,
                                                    float* __restrict__ th)
{
    int row = blockIdx.x;
    int t = threadIdx.x;
    const float* hp = h + (long)row * CFF;
    float v = hp[t] * W2[t] + hp[t + 64] * W2[t + 64];
    v = waveReduceSum(v);
    if (t == 0) th[row] = v + b2[0];
}

// weight prep: W[K,N] f32 -> WT hi/lo f16 [N,K]
__global__ __launch_bounds__(256) void wprep(const float* __restrict__ W,
                                             half_t* __restrict__ Th, half_t* __restrict__ Tl,
                                             int K, int N)
{
    __shared__ float tw[32][33];
    int n0 = blockIdx.x * 32, k0 = blockIdx.y * 32;
    int c = threadIdx.x & 31, r8 = threadIdx.x >> 5;
#pragma unroll
    for (int i = 0; i < 4; ++i) {
        int r = r8 + i * 8;
        tw[r][c] = W[(long)(k0 + r) * N + n0 + c];
    }
    __syncthreads();
#pragma unroll
    for (int i = 0; i < 4; ++i) {
        int nr = r8 + i * 8;              // output row (n)
        float v = tw[c][nr];
        half_t hh = (half_t)v;
        Th[(long)(n0 + nr) * K + k0 + c] = hh;
        Tl[(long)(n0 + nr) * K + k0 + c] = (half_t)(v - (float)hh);
    }
}

// X f32 -> hi/lo f16 (no transpose)
__global__ __launch_bounds__(256) void split_f32(const float* __restrict__ in,
                                                 half_t* __restrict__ hi, half_t* __restrict__ lo)
{
    long i = ((long)blockIdx.x * 256 + threadIdx.x) * 8;
    float4 a = *(const float4*)(in + i), b = *(const float4*)(in + i + 4);
    float v[8] = {a.x, a.y, a.z, a.w, b.x, b.y, b.z, b.w};
    half8 hv, lv;
#pragma unroll
    for (int j = 0; j < 8; ++j) {
        half_t hh = (half_t)v[j];
        hv[j] = hh;
        lv[j] = (half_t)(v[j] - (float)hh);
    }
    *(half8*)(hi + i) = hv;
    *(half8*)(lo + i) = lv;
}

// batched f16-pair transpose: in [8][2048][512] -> out [8][512][2048]
__global__ __launch_bounds__(256) void transpose_pair(const half_t* __restrict__ ih, const half_t* __restrict__ il,
                                                      half_t* __restrict__ oh, half_t* __restrict__ ol)
{
    __shared__ half_t th[64][66], tl[64][66];
    int b = blockIdx.z;
    int c0 = blockIdx.x * 64;   // in-col / out-row tile
    int r0 = blockIdx.y * 64;   // in-row / out-col tile
    const half_t* pih = ih + ((long)b * 2048 + r0) * 512 + c0;
    const half_t* pil = il + ((long)b * 2048 + r0) * 512 + c0;
    int t = threadIdx.x;
    int cc = (t & 7) * 8, rr = t >> 3;   // rr 0..31
#pragma unroll
    for (int i = 0; i < 2; ++i) {
        int r = rr + 32 * i;
        *(uint4v*)&th[r][cc] = *(const uint4v*)(pih + (long)r * 512 + cc);
        *(uint4v*)&tl[r][cc] = *(const uint4v*)(pil + (long)r * 512 + cc);
    }
    __syncthreads();
    half_t* poh = oh + ((long)b * 512 + c0) * 2048 + r0;
    half_t* pol = ol + ((long)b * 512 + c0) * 2048 + r0;
#pragma unroll
    for (int i = 0; i < 2; ++i) {
        int ic = rr + 32 * i;            // out row (= in col)
        half8 vh, vl;
#pragma unroll
        for (int j = 0; j < 8; ++j) {
            vh[j] = th[cc + j][ic];
            vl[j] = tl[cc + j][ic];
        }
        *(half8*)(poh + (long)ic * 2048 + cc) = vh;
        *(half8*)(pol + (long)ic * 2048 + cc) = vl;
    }
}

// ============================================================================
// host-side dispatch
// ============================================================================
static void launch_gemm16(hipStream_t s, int epi,
    const half_t* Ahi, const half_t* Alo, long lda, long sA,
    const half_t* Bhi, const half_t* Blo, long ldb, long sB,
    float* Cf, half_t* Chi, half_t* Clo, long ldc, long sC,
    int M, int N, int K, int batch, float alpha, const float* bias, const float* tvec)
{
    dim3 g(N / 128, M / 128, batch), b(256, 1, 1);
    if (epi == 0)      gemm_f16s<0><<<g, b, 0, s>>>(Ahi, Alo, lda, sA, Bhi, Blo, ldb, sB, Cf, Chi, Clo, ldc, sC, K, alpha, bias, tvec);
    else if (epi == 1) gemm_f16s<1><<<g, b, 0, s>>>(Ahi, Alo, lda, sA, Bhi, Blo, ldb, sB, Cf, Chi, Clo, ldc, sC, K, alpha, bias, tvec);
    else if (epi == 2) gemm_f16s<2><<<g, b, 0, s>>>(Ahi, Alo, lda, sA, Bhi, Blo, ldb, sB, Cf, Chi, Clo, ldc, sC, K, alpha, bias, tvec);
    else               gemm_f16s<3><<<g, b, 0, s>>>(Ahi, Alo, lda, sA, Bhi, Blo, ldb, sB, Cf, Chi, Clo, ldc, sC, K, alpha, bias, tvec);
}

extern "C" void kernel_launch(void* const* d_in, const int* in_sizes, int n_in,
                              void* d_out, int out_size, void* d_ws, size_t ws_size,
                              hipStream_t stream)
{
    const float* X   = (const float*)d_in[0];
    const float* Wq1 = (const float*)d_in[1];
    const float* Wk1 = (const float*)d_in[2];
    const float* Wv1 = (const float*)d_in[3];
    const float* Wo1 = (const float*)d_in[4];
    const float* Wq2 = (const float*)d_in[5];
    const float* Wk2 = (const float*)d_in[6];
    const float* W1  = (const float*)d_in[7];
    const float* b1  = (const float*)d_in[8];
    const float* W2  = (const float*)d_in[9];
    const float* b2  = (const float*)d_in[10];

    float* out = (float*)d_out;
    const float scale = 0.044194173824159216f;   // 1/sqrt(512)

    // ---- workspace layout (f16 elements) ----
    half_t* wsH = (half_t*)d_ws;
    const long U  = (long)MT * DD;               // 8,388,608
    const long WD = (long)DD * DD;               // 262,144
    half_t* sAh = wsH;          half_t* sAl = wsH + U;        // slot A
    half_t* sBh = wsH + 2 * U;  half_t* sBl = wsH + 3 * U;    // slot B
    half_t* sCh = wsH + 4 * U;  half_t* sCl = wsH + 5 * U;    // slot C
    half_t* wt  = wsH + 6 * U;                                // weights region
    half_t* wq1h = wt;              half_t* wq1l = wq1h + WD;
    half_t* wk1h = wq1l + WD;       half_t* wk1l = wk1h + WD;
    half_t* wv1h = wk1l + WD;       half_t* wv1l = wv1h + WD;
    half_t* wo1h = wv1l + WD;       half_t* wo1l = wo1h + WD;
    half_t* wq2h = wo1l + WD;       half_t* wq2l = wq2h + WD;
    half_t* wk2h = wq2l + WD;       half_t* wk2l = wk2h + WD;
    half_t* w1h  = wk2l + WD;       half_t* w1l  = w1h + (long)DD * CFF;
    float*  thresh = (float*)(w1l + (long)DD * CFF);
    float*  sums   = thresh + MT;
    // h [16384,128] f32 parked in d_out (dead region between PV and surv)
    float* h = out;

    // ---- prep: split X, transpose+split weights ----
    split_f32<<<dim3(4096), dim3(256), 0, stream>>>(X, sAh, sAl);
    wprep<<<dim3(16, 16), dim3(256), 0, stream>>>(Wq1, wq1h, wq1l, DD, DD);
    wprep<<<dim3(16, 16), dim3(256), 0, stream>>>(Wk1, wk1h, wk1l, DD, DD);
    wprep<<<dim3(16, 16), dim3(256), 0, stream>>>(Wv1, wv1h, wv1l, DD, DD);
    wprep<<<dim3(16, 16), dim3(256), 0, stream>>>(Wo1, wo1h, wo1l, DD, DD);
    wprep<<<dim3(16, 16), dim3(256), 0, stream>>>(Wq2, wq2h, wq2l, DD, DD);
    wprep<<<dim3(16, 16), dim3(256), 0, stream>>>(Wk2, wk2h, wk2l, DD, DD);
    wprep<<<dim3(4, 16),  dim3(256), 0, stream>>>(W1,  w1h,  w1l,  DD, CFF);

    // 1) q1 = X@Wq1 -> slotB ; k1 = X@Wk1 -> slotC   (hi/lo split outputs)
    launch_gemm16(stream, 1, sAh, sAl, DD, 0, wq1h, wq1l, DD, 0,
                  nullptr, sBh, sBl, DD, 0, MT, DD, DD, 1, 1.f, nullptr, nullptr);
    launch_gemm16(stream, 1, sAh, sAl, DD, 0, wk1h, wk1l, DD, 0,
                  nullptr, sCh, sCl, DD, 0, MT, DD, DD, 1, 1.f, nullptr, nullptr);

    // 2) s1 = scale * q1 @ k1^T  (batched) -> d_out f32
    launch_gemm16(stream, 0, sBh, sBl, DD, (long)NN * DD, sCh, sCl, DD, (long)NN * DD,
                  out, nullptr, nullptr, NN, (long)NN * NN, NN, NN, DD, BB, scale, nullptr, nullptr);

    // 3) v1 = X@Wv1 -> slotB (q1 dead after s1)
    launch_gemm16(stream, 1, sAh, sAl, DD, 0, wv1h, wv1l, DD, 0,
                  nullptr, sBh, sBl, DD, 0, MT, DD, DD, 1, 1.f, nullptr, nullptr);

    // 4) softmax(s1) -> p1 hi/lo f16 in place in d_out (hi at row*4096, lo +2048)
    softmax_split_kernel<<<dim3(MT), dim3(256), 0, stream>>>(out);

    // 5) v1T = transpose(v1) per batch -> slotC (k1 dead)
    transpose_pair<<<dim3(8, 32, BB), dim3(256), 0, stream>>>(sBh, sBl, sCh, sCl);

    // 6) attout = p1 @ v1 (batched) -> slotB hi/lo (v1 dead)
    {
        const half_t* p1h = (const half_t*)d_out;
        const half_t* p1l = p1h + NN;
        launch_gemm16(stream, 1, p1h, p1l, 2 * NN, (long)NN * 2 * NN,
                      sCh, sCl, NN, (long)DD * NN,
                      nullptr, sBh, sBl, DD, (long)NN * DD, NN, DD, NN, BB, 1.f, nullptr, nullptr);
    }

    // 7) att = attout @ Wo1 -> slotC (v1T dead)
    launch_gemm16(stream, 1, sBh, sBl, DD, 0, wo1h, wo1l, DD, 0,
                  nullptr, sCh, sCl, DD, 0, MT, DD, DD, 1, 1.f, nullptr, nullptr);

    // 8) q2 = att@Wq2 -> slotA (X dead) ; k2 = att@Wk2 -> slotB (attout dead)
    launch_gemm16(stream, 1, sCh, sCl, DD, 0, wq2h, wq2l, DD, 0,
                  nullptr, sAh, sAl, DD, 0, MT, DD, DD, 1, 1.f, nullptr, nullptr);
    launch_gemm16(stream, 1, sCh, sCl, DD, 0, wk2h, wk2l, DD, 0,
                  nullptr, sBh, sBl, DD, 0, MT, DD, DD, 1, 1.f, nullptr, nullptr);

    // 9) h = leakyrelu(att@W1 + b1) -> d_out region (p1 dead after step 6)
    launch_gemm16(stream, 2, sCh, sCl, DD, 0, w1h, w1l, DD, 0,
                  h, nullptr, nullptr, CFF, 0, MT, CFF, DD, 1, 1.f, b1, nullptr);

    // 10) thresh = h@W2 + b2
    thresh_kernel<<<dim3(MT), dim3(64), 0, stream>>>(h, W2, b2, thresh);

    // 11) surv = max(scale * q2@k2^T - thresh[row], 0) (batched) -> d_out
    launch_gemm16(stream, 3, sAh, sAl, DD, (long)NN * DD, sBh, sBl, DD, (long)NN * DD,
                  out, nullptr, nullptr, NN, (long)NN * NN, NN, NN, DD, BB, scale, nullptr, thresh);

    // 12) row sums ; 13) normalize+clip
    rowsum_kernel<<<dim3(MT), dim3(256), 0, stream>>>(out, sums);
    norm_kernel<<<dim3(out_size / 1024), dim3(256), 0, stream>>>(out, sums);
}

// Round 3
// 808.318 us; speedup vs baseline: 2.5853x; 1.1135x over previous
//
#include <hip/hip_runtime.h>
#include <hip/hip_bf16.h>

// Problem constants
#define BB 8
#define NN 2048
#define DD 512
#define CFF 128
#define MT (BB*NN)   // 16384

typedef _Float16 half_t;
typedef __attribute__((ext_vector_type(8))) _Float16 half8;
typedef __attribute__((ext_vector_type(4))) float floatx4;
typedef __attribute__((ext_vector_type(4))) unsigned int uint4v;

#define MFMA16(a,b,c) __builtin_amdgcn_mfma_f32_16x16x32_f16((a),(b),(c),0,0,0)

// ============================================================================
// fp16-split MFMA GEMM:  C = epi( alpha * (Ahi+Alo) @ (Bhi+Blo)^T )
// A: [M,K] row-major (lda), B: [N,K] row-major (ldb), hi/lo f16 pre-split.
// 3-pass Markidis: hi*hi + lo*hi + hi*lo. Tile 128x128, BK=32, 4 waves 64x64.
// XCD-chunked tile swizzle (T1): consecutive logical tiles -> same XCD ->
// A/B re-reads become L2 hits (batched shapes: exactly one batch per XCD).
// EPI: 0 = alpha*acc -> Cf
//      1 = hi/lo split -> Chi/Clo, multi-slot by col>>9 (stride slotS)
//      3 = max(alpha*acc - tvec[z*NN+row],0) -> Cf, + atomicAdd row partials to rsum
//      4 = leakyrelu(acc+bias[col]) dotted with tvec(=W2) -> atomicAdd rsum(=thresh)
// ============================================================================
template<int EPI>
__global__ __launch_bounds__(256) void gemm_f16s(
    const half_t* __restrict__ Ahi, const half_t* __restrict__ Alo, long lda, long sA,
    const half_t* __restrict__ Bhi, const half_t* __restrict__ Blo, long ldb, long sB,
    float* __restrict__ Cf, half_t* __restrict__ Chi, half_t* __restrict__ Clo,
    long ldc, long sC, long slotS,
    int K, float alpha, const float* __restrict__ bias, const float* __restrict__ tvec,
    float* __restrict__ rsum)
{
    // ---- XCD-chunked swizzle (all grids have total % 8 == 0) ----
    const int gx = gridDim.x, gy = gridDim.y;
    int d = blockIdx.x + gx * (blockIdx.y + gy * blockIdx.z);
    int total = gx * gy * gridDim.z;
    int t0 = (d & 7) * (total >> 3) + (d >> 3);
    int bx = t0 % gx;
    int t1 = t0 / gx;
    int by = t1 % gy;
    int bz = t1 / gy;

    const int tid = threadIdx.x;
    const int row0 = by * 128, col0 = bx * 128;
    const long z = bz;
    const half_t* pAh = Ahi + z * sA + (long)row0 * lda;
    const half_t* pAl = Alo + z * sA + (long)row0 * lda;
    const half_t* pBh = Bhi + z * sB + (long)col0 * ldb;
    const half_t* pBl = Blo + z * sB + (long)col0 * ldb;

    __shared__ half_t lds[2][4][4096];   // [buf][Ah,Al,Bh,Bl][128*32]

    const int l  = tid & 63;
    const int w  = tid >> 6;
    const int wr = w >> 1, wc = w & 1;
    const int Rw = wr * 64, Cw = wc * 64;
    const int rl = l & 15, kc = l >> 4;        // frag row/col, k-chunk
    const int swz = (kc ^ (rl & 3)) * 8;       // swizzled k-offset (elems)

    floatx4 acc[4][4];
#pragma unroll
    for (int m = 0; m < 4; ++m)
#pragma unroll
        for (int n = 0; n < 4; ++n) acc[m][n] = (floatx4){0.f, 0.f, 0.f, 0.f};

    const int r0s = tid >> 2,         c0s = tid & 3;
    const int r1s = (tid + 256) >> 2, c1s = tid & 3;
    const int off0 = r0s * 32 + ((c0s ^ (r0s & 3)) * 8);
    const int off1 = r1s * 32 + ((c1s ^ (r1s & 3)) * 8);

    auto stage = [&](int buf, int k0) {
        long ga0 = (long)r0s * lda + k0 + c0s * 8;
        long gb0 = (long)r0s * ldb + k0 + c0s * 8;
        long ga1 = (long)r1s * lda + k0 + c1s * 8;
        long gb1 = (long)r1s * ldb + k0 + c1s * 8;
        uint4v a0 = *(const uint4v*)(pAh + ga0);
        uint4v a1 = *(const uint4v*)(pAl + ga0);
        uint4v b0 = *(const uint4v*)(pBh + gb0);
        uint4v b1 = *(const uint4v*)(pBl + gb0);
        uint4v a2 = *(const uint4v*)(pAh + ga1);
        uint4v a3 = *(const uint4v*)(pAl + ga1);
        uint4v b2 = *(const uint4v*)(pBh + gb1);
        uint4v b3 = *(const uint4v*)(pBl + gb1);
        *(uint4v*)&lds[buf][0][off0] = a0;
        *(uint4v*)&lds[buf][1][off0] = a1;
        *(uint4v*)&lds[buf][2][off0] = b0;
        *(uint4v*)&lds[buf][3][off0] = b1;
        *(uint4v*)&lds[buf][0][off1] = a2;
        *(uint4v*)&lds[buf][1][off1] = a3;
        *(uint4v*)&lds[buf][2][off1] = b2;
        *(uint4v*)&lds[buf][3][off1] = b3;
    };

    const int nk = K >> 5;
    stage(0, 0);
#pragma unroll 2
    for (int t = 0; t < nk; ++t) {
        __syncthreads();
        const int cur = t & 1;
        const half_t* bAh = &lds[cur][0][0];
        const half_t* bAl = &lds[cur][1][0];
        const half_t* bBh = &lds[cur][2][0];
        const half_t* bBl = &lds[cur][3][0];
        half8 af[4][2], bf[4][2];
#pragma unroll
        for (int m = 0; m < 4; ++m) {
            int off = (Rw + m * 16 + rl) * 32 + swz;
            af[m][0] = *(const half8*)(bAh + off);
            af[m][1] = *(const half8*)(bAl + off);
        }
#pragma unroll
        for (int n = 0; n < 4; ++n) {
            int off = (Cw + n * 16 + rl) * 32 + swz;
            bf[n][0] = *(const half8*)(bBh + off);
            bf[n][1] = *(const half8*)(bBl + off);
        }
#pragma unroll
        for (int m = 0; m < 4; ++m)
#pragma unroll
            for (int n = 0; n < 4; ++n) {
                acc[m][n] = MFMA16(af[m][0], bf[n][0], acc[m][n]);
                acc[m][n] = MFMA16(af[m][1], bf[n][0], acc[m][n]);
                acc[m][n] = MFMA16(af[m][0], bf[n][1], acc[m][n]);
            }
        if (t + 1 < nk) stage((t + 1) & 1, (t + 1) << 5);
    }

    // ---- epilogue — C/D frag: col = lane&15, row = (lane>>4)*4 + reg ----
    if (EPI == 0) {
#pragma unroll
        for (int m = 0; m < 4; ++m)
#pragma unroll
            for (int n = 0; n < 4; ++n) {
                int col = col0 + Cw + n * 16 + rl;
#pragma unroll
                for (int r = 0; r < 4; ++r) {
                    int row = row0 + Rw + m * 16 + kc * 4 + r;
                    Cf[z * sC + (long)row * ldc + col] = acc[m][n][r] * alpha;
                }
            }
    } else if (EPI == 1) {
#pragma unroll
        for (int m = 0; m < 4; ++m)
#pragma unroll
            for (int n = 0; n < 4; ++n) {
                int col = col0 + Cw + n * 16 + rl;
                long obase = (long)(col >> 9) * slotS + z * sC + (col & 511);
#pragma unroll
                for (int r = 0; r < 4; ++r) {
                    int row = row0 + Rw + m * 16 + kc * 4 + r;
                    long o = obase + (long)row * ldc;
                    float v = acc[m][n][r];
                    half_t hh = (half_t)v;
                    Chi[o] = hh;
                    Clo[o] = (half_t)(v - (float)hh);
                }
            }
    } else if (EPI == 3) {
        const float* tv = tvec + z * NN;
        float* rs = rsum + z * NN;
#pragma unroll
        for (int m = 0; m < 4; ++m) {
#pragma unroll
            for (int r = 0; r < 4; ++r) {
                int row = row0 + Rw + m * 16 + kc * 4 + r;
                float tvr = tv[row];
                float partial = 0.f;
#pragma unroll
                for (int n = 0; n < 4; ++n) {
                    int col = col0 + Cw + n * 16 + rl;
                    float v = fmaxf(acc[m][n][r] * alpha - tvr, 0.f);
                    Cf[z * sC + (long)row * ldc + col] = v;
                    partial += v;
                }
                partial += __shfl_xor(partial, 1);
                partial += __shfl_xor(partial, 2);
                partial += __shfl_xor(partial, 4);
                partial += __shfl_xor(partial, 8);
                if (rl == 0) atomicAdd(&rs[row], partial);
            }
        }
    } else {  // EPI == 4: fused h + thresh (bias=b1, tvec=W2, rsum=thresh)
        float w2v[4], bv[4];
#pragma unroll
        for (int n = 0; n < 4; ++n) {
            int col = Cw + n * 16 + rl;
            bv[n]  = bias[col];
            w2v[n] = tvec[col];
        }
#pragma unroll
        for (int m = 0; m < 4; ++m) {
#pragma unroll
            for (int r = 0; r < 4; ++r) {
                int row = row0 + Rw + m * 16 + kc * 4 + r;
                float partial = 0.f;
#pragma unroll
                for (int n = 0; n < 4; ++n) {
                    float v = acc[m][n][r] + bv[n];
                    v = (v >= 0.f) ? v : 0.1f * v;
                    partial += v * w2v[n];
                }
                partial += __shfl_xor(partial, 1);
                partial += __shfl_xor(partial, 2);
                partial += __shfl_xor(partial, 4);
                partial += __shfl_xor(partial, 8);
                if (rl == 0) atomicAdd(&rsum[row], partial);
            }
        }
    }
}

// ============================================================================
// helpers
// ============================================================================
__device__ __forceinline__ float waveReduceMax(float v) {
#pragma unroll
    for (int o = 32; o; o >>= 1) v = fmaxf(v, __shfl_down(v, o));
    return v;
}
__device__ __forceinline__ float waveReduceSum(float v) {
#pragma unroll
    for (int o = 32; o; o >>= 1) v += __shfl_down(v, o);
    return v;
}

// softmax over rows of 2048 f32 (in d_out); writes p1 hi/lo f16 IN PLACE:
// hi at f16-offset row*4096, lo at row*4096+2048.
__global__ __launch_bounds__(256) void softmax_split_kernel(float* __restrict__ S)
{
    __shared__ float red[4];
    __shared__ float fin;
    long row = blockIdx.x;
    float* p = S + row * (long)NN;
    half_t* ph = (half_t*)p;
    half_t* pl = ph + NN;
    int t = threadIdx.x;

    float4 v0 = *reinterpret_cast<float4*>(p + t * 8);
    float4 v1 = *reinterpret_cast<float4*>(p + t * 8 + 4);

    float m = fmaxf(fmaxf(fmaxf(v0.x, v0.y), fmaxf(v0.z, v0.w)),
                    fmaxf(fmaxf(v1.x, v1.y), fmaxf(v1.z, v1.w)));
    m = waveReduceMax(m);
    if ((t & 63) == 0) red[t >> 6] = m;
    __syncthreads();
    if (t == 0) fin = fmaxf(fmaxf(red[0], red[1]), fmaxf(red[2], red[3]));
    __syncthreads();
    m = fin;

    float e[8];
    e[0] = __expf(v0.x - m); e[1] = __expf(v0.y - m); e[2] = __expf(v0.z - m); e[3] = __expf(v0.w - m);
    e[4] = __expf(v1.x - m); e[5] = __expf(v1.y - m); e[6] = __expf(v1.z - m); e[7] = __expf(v1.w - m);
    float s = ((e[0] + e[1]) + (e[2] + e[3])) + ((e[4] + e[5]) + (e[6] + e[7]));
    s = waveReduceSum(s);
    __syncthreads();
    if ((t & 63) == 0) red[t >> 6] = s;
    __syncthreads();
    if (t == 0) fin = (red[0] + red[1]) + (red[2] + red[3]);
    __syncthreads();
    float inv = 1.0f / fin;

    __syncthreads();
    half8 hv, lv;
#pragma unroll
    for (int j = 0; j < 8; ++j) {
        float pv = e[j] * inv;
        half_t hh = (half_t)pv;
        hv[j] = hh;
        lv[j] = (half_t)(pv - (float)hh);
    }
    *(half8*)(ph + t * 8) = hv;
    *(half8*)(pl + t * 8) = lv;
}

// A = clip(surv / (sum+1e-9), 0, 1) in place, 8 floats/thread
__global__ __launch_bounds__(256) void norm_kernel(float* __restrict__ S, const float* __restrict__ sums)
{
    long i = (long)blockIdx.x * 256 + threadIdx.x;
    long base = i * 8;
    long row = base >> 11;   // NN = 2048
    float inv = 1.0f / (sums[row] + 1e-9f);
    float4 v0 = *reinterpret_cast<float4*>(S + base);
    float4 v1 = *reinterpret_cast<float4*>(S + base + 4);
    v0.x = fminf(v0.x * inv, 1.0f); v0.y = fminf(v0.y * inv, 1.0f);
    v0.z = fminf(v0.z * inv, 1.0f); v0.w = fminf(v0.w * inv, 1.0f);
    v1.x = fminf(v1.x * inv, 1.0f); v1.y = fminf(v1.y * inv, 1.0f);
    v1.z = fminf(v1.z * inv, 1.0f); v1.w = fminf(v1.w * inv, 1.0f);
    *reinterpret_cast<float4*>(S + base) = v0;
    *reinterpret_cast<float4*>(S + base + 4) = v1;
}

// thresh[i] = b2 ; sums[i] = 0
__global__ __launch_bounds__(256) void init_aux(float* __restrict__ thresh, float* __restrict__ sums,
                                                const float* __restrict__ b2)
{
    int i = blockIdx.x * 256 + threadIdx.x;
    if (i < MT) { thresh[i] = b2[0]; sums[i] = 0.f; }
}

// weight prep: W[K,N] f32 -> WT hi/lo f16 [N,K]
__global__ __launch_bounds__(256) void wprep(const float* __restrict__ W,
                                             half_t* __restrict__ Th, half_t* __restrict__ Tl,
                                             int K, int N)
{
    __shared__ float tw[32][33];
    int n0 = blockIdx.x * 32, k0 = blockIdx.y * 32;
    int c = threadIdx.x & 31, r8 = threadIdx.x >> 5;
#pragma unroll
    for (int i = 0; i < 4; ++i) {
        int r = r8 + i * 8;
        tw[r][c] = W[(long)(k0 + r) * N + n0 + c];
    }
    __syncthreads();
#pragma unroll
    for (int i = 0; i < 4; ++i) {
        int nr = r8 + i * 8;
        float v = tw[c][nr];
        half_t hh = (half_t)v;
        Th[(long)(n0 + nr) * K + k0 + c] = hh;
        Tl[(long)(n0 + nr) * K + k0 + c] = (half_t)(v - (float)hh);
    }
}

// X f32 -> hi/lo f16 (no transpose)
__global__ __launch_bounds__(256) void split_f32(const float* __restrict__ in,
                                                 half_t* __restrict__ hi, half_t* __restrict__ lo)
{
    long i = ((long)blockIdx.x * 256 + threadIdx.x) * 8;
    float4 a = *(const float4*)(in + i), b = *(const float4*)(in + i + 4);
    float v[8] = {a.x, a.y, a.z, a.w, b.x, b.y, b.z, b.w};
    half8 hv, lv;
#pragma unroll
    for (int j = 0; j < 8; ++j) {
        half_t hh = (half_t)v[j];
        hv[j] = hh;
        lv[j] = (half_t)(v[j] - (float)hh);
    }
    *(half8*)(hi + i) = hv;
    *(half8*)(lo + i) = lv;
}

// batched f16-pair transpose: in [8][2048][512] -> out [8][512][2048]
__global__ __launch_bounds__(256) void transpose_pair(const half_t* __restrict__ ih, const half_t* __restrict__ il,
                                                      half_t* __restrict__ oh, half_t* __restrict__ ol)
{
    __shared__ half_t th[64][66], tl[64][66];
    int b = blockIdx.z;
    int c0 = blockIdx.x * 64;
    int r0 = blockIdx.y * 64;
    const half_t* pih = ih + ((long)b * 2048 + r0) * 512 + c0;
    const half_t* pil = il + ((long)b * 2048 + r0) * 512 + c0;
    int t = threadIdx.x;
    int cc = (t & 7) * 8, rr = t >> 3;
#pragma unroll
    for (int i = 0; i < 2; ++i) {
        int r = rr + 32 * i;
        *(uint4v*)&th[r][cc] = *(const uint4v*)(pih + (long)r * 512 + cc);
        *(uint4v*)&tl[r][cc] = *(const uint4v*)(pil + (long)r * 512 + cc);
    }
    __syncthreads();
    half_t* poh = oh + ((long)b * 512 + c0) * 2048 + r0;
    half_t* pol = ol + ((long)b * 512 + c0) * 2048 + r0;
#pragma unroll
    for (int i = 0; i < 2; ++i) {
        int ic = rr + 32 * i;
        half8 vh, vl;
#pragma unroll
        for (int j = 0; j < 8; ++j) {
            vh[j] = th[cc + j][ic];
            vl[j] = tl[cc + j][ic];
        }
        *(half8*)(poh + (long)ic * 2048 + cc) = vh;
        *(half8*)(pol + (long)ic * 2048 + cc) = vl;
    }
}

// ============================================================================
// host-side dispatch
// ============================================================================
static void launch_gemm16(hipStream_t s, int epi,
    const half_t* Ahi, const half_t* Alo, long lda, long sA,
    const half_t* Bhi, const half_t* Blo, long ldb, long sB,
    float* Cf, half_t* Chi, half_t* Clo, long ldc, long sC, long slotS,
    int M, int N, int K, int batch, float alpha,
    const float* bias, const float* tvec, float* rsum)
{
    dim3 g(N / 128, M / 128, batch), b(256, 1, 1);
    if (epi == 0)      gemm_f16s<0><<<g, b, 0, s>>>(Ahi, Alo, lda, sA, Bhi, Blo, ldb, sB, Cf, Chi, Clo, ldc, sC, slotS, K, alpha, bias, tvec, rsum);
    else if (epi == 1) gemm_f16s<1><<<g, b, 0, s>>>(Ahi, Alo, lda, sA, Bhi, Blo, ldb, sB, Cf, Chi, Clo, ldc, sC, slotS, K, alpha, bias, tvec, rsum);
    else if (epi == 3) gemm_f16s<3><<<g, b, 0, s>>>(Ahi, Alo, lda, sA, Bhi, Blo, ldb, sB, Cf, Chi, Clo, ldc, sC, slotS, K, alpha, bias, tvec, rsum);
    else               gemm_f16s<4><<<g, b, 0, s>>>(Ahi, Alo, lda, sA, Bhi, Blo, ldb, sB, Cf, Chi, Clo, ldc, sC, slotS, K, alpha, bias, tvec, rsum);
}

extern "C" void kernel_launch(void* const* d_in, const int* in_sizes, int n_in,
                              void* d_out, int out_size, void* d_ws, size_t ws_size,
                              hipStream_t stream)
{
    const float* X   = (const float*)d_in[0];
    const float* Wq1 = (const float*)d_in[1];
    const float* Wk1 = (const float*)d_in[2];
    const float* Wv1 = (const float*)d_in[3];
    const float* Wo1 = (const float*)d_in[4];
    const float* Wq2 = (const float*)d_in[5];
    const float* Wk2 = (const float*)d_in[6];
    const float* W1  = (const float*)d_in[7];
    const float* b1  = (const float*)d_in[8];
    const float* W2  = (const float*)d_in[9];
    const float* b2  = (const float*)d_in[10];

    float* out = (float*)d_out;
    const float scale = 0.044194173824159216f;   // 1/sqrt(512)

    // ---- workspace layout (f16 elements) ----
    half_t* wsH = (half_t*)d_ws;
    const long U  = (long)MT * DD;               // 8,388,608
    const long WD = (long)DD * DD;               // 262,144
    half_t* sAh = wsH;          half_t* sAl = wsH + U;        // slot A
    half_t* sBh = wsH + 2 * U;  half_t* sBl = wsH + 3 * U;    // slot B
    half_t* sCh = wsH + 4 * U;  half_t* sCl = wsH + 5 * U;    // slot C
    half_t* wt  = wsH + 6 * U;
    // merged-weight layout: [Wq1T|Wk1T] hi then lo; Wv1T; Wo1T; [Wq2T|Wk2T]; W1T
    half_t* wqk1h = wt;               half_t* wqk1l = wqk1h + 2 * WD;
    half_t* wv1h  = wqk1l + 2 * WD;   half_t* wv1l  = wv1h + WD;
    half_t* wo1h  = wv1l + WD;        half_t* wo1l  = wo1h + WD;
    half_t* wqk2h = wo1l + WD;        half_t* wqk2l = wqk2h + 2 * WD;
    half_t* w1h   = wqk2l + 2 * WD;   half_t* w1l   = w1h + (long)DD * CFF;
    float*  thresh = (float*)(w1l + (long)DD * CFF);
    float*  sums   = thresh + MT;

    // ---- prep ----
    init_aux<<<dim3(64), dim3(256), 0, stream>>>(thresh, sums, b2);
    split_f32<<<dim3(4096), dim3(256), 0, stream>>>(X, sAh, sAl);
    wprep<<<dim3(16, 16), dim3(256), 0, stream>>>(Wq1, wqk1h,      wqk1l,      DD, DD);
    wprep<<<dim3(16, 16), dim3(256), 0, stream>>>(Wk1, wqk1h + WD, wqk1l + WD, DD, DD);
    wprep<<<dim3(16, 16), dim3(256), 0, stream>>>(Wv1, wv1h,  wv1l,  DD, DD);
    wprep<<<dim3(16, 16), dim3(256), 0, stream>>>(Wo1, wo1h,  wo1l,  DD, DD);
    wprep<<<dim3(16, 16), dim3(256), 0, stream>>>(Wq2, wqk2h,      wqk2l,      DD, DD);
    wprep<<<dim3(16, 16), dim3(256), 0, stream>>>(Wk2, wqk2h + WD, wqk2l + WD, DD, DD);
    wprep<<<dim3(4, 16),  dim3(256), 0, stream>>>(W1,  w1h,   w1l,   DD, CFF);

    // 1) [q1|k1] = X @ [Wq1|Wk1]  -> slots B,C  (N=1024, multi-slot, slotS=2U)
    launch_gemm16(stream, 1, sAh, sAl, DD, 0, wqk1h, wqk1l, DD, 0,
                  nullptr, sBh, sBl, DD, 0, 2 * U, MT, 2 * DD, DD, 1, 1.f, nullptr, nullptr, nullptr);

    // 2) s1 = scale * q1 @ k1^T (batched) -> d_out f32
    launch_gemm16(stream, 0, sBh, sBl, DD, (long)NN * DD, sCh, sCl, DD, (long)NN * DD,
                  out, nullptr, nullptr, NN, (long)NN * NN, 0, NN, NN, DD, BB, scale, nullptr, nullptr, nullptr);

    // 3) v1 = X @ Wv1 -> slot B (q1 dead after s1)
    launch_gemm16(stream, 1, sAh, sAl, DD, 0, wv1h, wv1l, DD, 0,
                  nullptr, sBh, sBl, DD, 0, 0, MT, DD, DD, 1, 1.f, nullptr, nullptr, nullptr);

    // 4) softmax(s1) -> p1 hi/lo f16 in place in d_out
    softmax_split_kernel<<<dim3(MT), dim3(256), 0, stream>>>(out);

    // 5) v1T -> slot C (k1 dead)
    transpose_pair<<<dim3(8, 32, BB), dim3(256), 0, stream>>>(sBh, sBl, sCh, sCl);

    // 6) attout = p1 @ v1 (batched) -> slot B (v1 dead after transpose)
    {
        const half_t* p1h = (const half_t*)d_out;
        const half_t* p1l = p1h + NN;
        launch_gemm16(stream, 1, p1h, p1l, 2 * NN, (long)NN * 2 * NN,
                      sCh, sCl, NN, (long)DD * NN,
                      nullptr, sBh, sBl, DD, (long)NN * DD, 0, NN, DD, NN, BB, 1.f, nullptr, nullptr, nullptr);
    }

    // 7) att = attout @ Wo1 -> slot C (v1T dead)
    launch_gemm16(stream, 1, sBh, sBl, DD, 0, wo1h, wo1l, DD, 0,
                  nullptr, sCh, sCl, DD, 0, 0, MT, DD, DD, 1, 1.f, nullptr, nullptr, nullptr);

    // 8) [q2|k2] = att @ [Wq2|Wk2] -> slots A,B (X, attout dead)
    launch_gemm16(stream, 1, sCh, sCl, DD, 0, wqk2h, wqk2l, DD, 0,
                  nullptr, sAh, sAl, DD, 0, 2 * U, MT, 2 * DD, DD, 1, 1.f, nullptr, nullptr, nullptr);

    // 9) fused h+thresh: thresh += leakyrelu(att@W1 + b1) @ W2   (no h in HBM)
    launch_gemm16(stream, 4, sCh, sCl, DD, 0, w1h, w1l, DD, 0,
                  nullptr, nullptr, nullptr, CFF, 0, 0, MT, CFF, DD, 1, 1.f, b1, W2, thresh);

    // 10) surv = max(scale * q2@k2^T - thresh, 0) -> d_out, + atomic row sums
    launch_gemm16(stream, 3, sAh, sAl, DD, (long)NN * DD, sBh, sBl, DD, (long)NN * DD,
                  out, nullptr, nullptr, NN, (long)NN * NN, 0, NN, NN, DD, BB, scale, nullptr, thresh, sums);

    // 11) A = clip(surv/(sum+1e-9), 0, 1)
    norm_kernel<<<dim3(out_size / 2048), dim3(256), 0, stream>>>(out, sums);
}

// Round 4
// 761.602 us; speedup vs baseline: 2.7438x; 1.0613x over previous
//
#include <hip/hip_runtime.h>
#include <hip/hip_bf16.h>

// Problem constants
#define BB 8
#define NN 2048
#define DD 512
#define CFF 128
#define MT (BB*NN)   // 16384

typedef _Float16 half_t;
typedef __attribute__((ext_vector_type(8))) _Float16 half8;
typedef __attribute__((ext_vector_type(4))) float floatx4;
typedef __attribute__((ext_vector_type(4))) unsigned int uint4v;

#define MFMA16(a,b,c) __builtin_amdgcn_mfma_f32_16x16x32_f16((a),(b),(c),0,0,0)

// ============================================================================
// fp16-split MFMA GEMM:  C = epi( alpha * (Ahi+Alo) @ (Bhi+Blo)^T )
// A: [M,K] row-major (lda), B: [N,K] row-major (ldb), hi/lo f16 pre-split.
// 3-pass Markidis: hi*hi + lo*hi + hi*lo. Tile 128x128, BK=32, 4 waves 64x64.
// T1 XCD-chunked tile swizzle; T14 reg-staging (loads issued before barrier,
// LDS writes after MFMA cluster).
// EPI: 0 = alpha*acc -> Cf
//      1 = alpha*acc, hi/lo split -> Chi/Clo (col>>9 slot logic; slotS=512
//          makes it the identity for ldc=2048 outputs)
//      3 = max(alpha*acc - tvec[z*NN+row],0) -> Cf, + atomicAdd row sums
//      4 = leakyrelu(acc+bias[col]) . tvec(=W2) -> atomicAdd rsum(=thresh)
// ============================================================================
template<int EPI>
__global__ __launch_bounds__(256) void gemm_f16s(
    const half_t* __restrict__ Ahi, const half_t* __restrict__ Alo, long lda, long sA,
    const half_t* __restrict__ Bhi, const half_t* __restrict__ Blo, long ldb, long sB,
    float* __restrict__ Cf, half_t* __restrict__ Chi, half_t* __restrict__ Clo,
    long ldc, long sC, long slotS,
    int K, float alpha, const float* __restrict__ bias, const float* __restrict__ tvec,
    float* __restrict__ rsum)
{
    // ---- XCD-chunked swizzle (all grids have total % 8 == 0) ----
    const int gx = gridDim.x, gy = gridDim.y;
    int d = blockIdx.x + gx * (blockIdx.y + gy * blockIdx.z);
    int total = gx * gy * gridDim.z;
    int t0 = (d & 7) * (total >> 3) + (d >> 3);
    int bx = t0 % gx;
    int t1 = t0 / gx;
    int by = t1 % gy;
    int bz = t1 / gy;

    const int tid = threadIdx.x;
    const int row0 = by * 128, col0 = bx * 128;
    const long z = bz;
    const half_t* pAh = Ahi + z * sA + (long)row0 * lda;
    const half_t* pAl = Alo + z * sA + (long)row0 * lda;
    const half_t* pBh = Bhi + z * sB + (long)col0 * ldb;
    const half_t* pBl = Blo + z * sB + (long)col0 * ldb;

    __shared__ half_t lds[2][4][4096];   // [buf][Ah,Al,Bh,Bl][128*32]

    const int l  = tid & 63;
    const int w  = tid >> 6;
    const int wr = w >> 1, wc = w & 1;
    const int Rw = wr * 64, Cw = wc * 64;
    const int rl = l & 15, kc = l >> 4;        // frag row/col, k-chunk
    const int swz = (kc ^ (rl & 3)) * 8;       // swizzled k-offset (elems)

    floatx4 acc[4][4];
#pragma unroll
    for (int m = 0; m < 4; ++m)
#pragma unroll
        for (int n = 0; n < 4; ++n) acc[m][n] = (floatx4){0.f, 0.f, 0.f, 0.f};

    const int r0s = tid >> 2,         c0s = tid & 3;
    const int r1s = (tid + 256) >> 2, c1s = tid & 3;
    const int off0 = r0s * 32 + ((c0s ^ (r0s & 3)) * 8);
    const int off1 = r1s * 32 + ((c1s ^ (r1s & 3)) * 8);

    auto load_regs = [&](int k0, uint4v* r) {
        long ga0 = (long)r0s * lda + k0 + c0s * 8;
        long gb0 = (long)r0s * ldb + k0 + c0s * 8;
        long ga1 = (long)r1s * lda + k0 + c1s * 8;
        long gb1 = (long)r1s * ldb + k0 + c1s * 8;
        r[0] = *(const uint4v*)(pAh + ga0);
        r[1] = *(const uint4v*)(pAl + ga0);
        r[2] = *(const uint4v*)(pBh + gb0);
        r[3] = *(const uint4v*)(pBl + gb0);
        r[4] = *(const uint4v*)(pAh + ga1);
        r[5] = *(const uint4v*)(pAl + ga1);
        r[6] = *(const uint4v*)(pBh + gb1);
        r[7] = *(const uint4v*)(pBl + gb1);
    };
    auto write_lds = [&](int buf, const uint4v* r) {
        *(uint4v*)&lds[buf][0][off0] = r[0];
        *(uint4v*)&lds[buf][1][off0] = r[1];
        *(uint4v*)&lds[buf][2][off0] = r[2];
        *(uint4v*)&lds[buf][3][off0] = r[3];
        *(uint4v*)&lds[buf][0][off1] = r[4];
        *(uint4v*)&lds[buf][1][off1] = r[5];
        *(uint4v*)&lds[buf][2][off1] = r[6];
        *(uint4v*)&lds[buf][3][off1] = r[7];
    };

    const int nk = K >> 5;
    uint4v rg[8];
    load_regs(0, rg);
    write_lds(0, rg);
#pragma unroll 2
    for (int t = 0; t < nk; ++t) {
        if (t + 1 < nk) load_regs((t + 1) << 5, rg);   // issue early: hide HBM/L2 latency
        __syncthreads();                               // buf[t&1] writes visible; buf[(t+1)&1] reads retired
        const int cur = t & 1;
        const half_t* bAh = &lds[cur][0][0];
        const half_t* bAl = &lds[cur][1][0];
        const half_t* bBh = &lds[cur][2][0];
        const half_t* bBl = &lds[cur][3][0];
        half8 af[4][2], bf[4][2];
#pragma unroll
        for (int m = 0; m < 4; ++m) {
            int off = (Rw + m * 16 + rl) * 32 + swz;
            af[m][0] = *(const half8*)(bAh + off);
            af[m][1] = *(const half8*)(bAl + off);
        }
#pragma unroll
        for (int n = 0; n < 4; ++n) {
            int off = (Cw + n * 16 + rl) * 32 + swz;
            bf[n][0] = *(const half8*)(bBh + off);
            bf[n][1] = *(const half8*)(bBl + off);
        }
#pragma unroll
        for (int m = 0; m < 4; ++m)
#pragma unroll
            for (int n = 0; n < 4; ++n) {
                acc[m][n] = MFMA16(af[m][0], bf[n][0], acc[m][n]);
                acc[m][n] = MFMA16(af[m][1], bf[n][0], acc[m][n]);
                acc[m][n] = MFMA16(af[m][0], bf[n][1], acc[m][n]);
            }
        if (t + 1 < nk) write_lds((t + 1) & 1, rg);    // write late (same barrier interval)
    }

    // ---- epilogue — C/D frag: col = lane&15, row = (lane>>4)*4 + reg ----
    if (EPI == 0) {
#pragma unroll
        for (int m = 0; m < 4; ++m)
#pragma unroll
            for (int n = 0; n < 4; ++n) {
                int col = col0 + Cw + n * 16 + rl;
#pragma unroll
                for (int r = 0; r < 4; ++r) {
                    int row = row0 + Rw + m * 16 + kc * 4 + r;
                    Cf[z * sC + (long)row * ldc + col] = acc[m][n][r] * alpha;
                }
            }
    } else if (EPI == 1) {
#pragma unroll
        for (int m = 0; m < 4; ++m)
#pragma unroll
            for (int n = 0; n < 4; ++n) {
                int col = col0 + Cw + n * 16 + rl;
                long obase = (long)(col >> 9) * slotS + z * sC + (col & 511);
#pragma unroll
                for (int r = 0; r < 4; ++r) {
                    int row = row0 + Rw + m * 16 + kc * 4 + r;
                    long o = obase + (long)row * ldc;
                    float v = acc[m][n][r] * alpha;
                    half_t hh = (half_t)v;
                    Chi[o] = hh;
                    Clo[o] = (half_t)(v - (float)hh);
                }
            }
    } else if (EPI == 3) {
        const float* tv = tvec + z * NN;
        float* rs = rsum + z * NN;
#pragma unroll
        for (int m = 0; m < 4; ++m) {
#pragma unroll
            for (int r = 0; r < 4; ++r) {
                int row = row0 + Rw + m * 16 + kc * 4 + r;
                float tvr = tv[row];
                float partial = 0.f;
#pragma unroll
                for (int n = 0; n < 4; ++n) {
                    int col = col0 + Cw + n * 16 + rl;
                    float v = fmaxf(acc[m][n][r] * alpha - tvr, 0.f);
                    Cf[z * sC + (long)row * ldc + col] = v;
                    partial += v;
                }
                partial += __shfl_xor(partial, 1);
                partial += __shfl_xor(partial, 2);
                partial += __shfl_xor(partial, 4);
                partial += __shfl_xor(partial, 8);
                if (rl == 0) atomicAdd(&rs[row], partial);
            }
        }
    } else {  // EPI == 4: fused h + thresh (bias=b1, tvec=W2, rsum=thresh)
        float w2v[4], bv[4];
#pragma unroll
        for (int n = 0; n < 4; ++n) {
            int col = Cw + n * 16 + rl;
            bv[n]  = bias[col];
            w2v[n] = tvec[col];
        }
#pragma unroll
        for (int m = 0; m < 4; ++m) {
#pragma unroll
            for (int r = 0; r < 4; ++r) {
                int row = row0 + Rw + m * 16 + kc * 4 + r;
                float partial = 0.f;
#pragma unroll
                for (int n = 0; n < 4; ++n) {
                    float v = acc[m][n][r] + bv[n];
                    v = (v >= 0.f) ? v : 0.1f * v;
                    partial += v * w2v[n];
                }
                partial += __shfl_xor(partial, 1);
                partial += __shfl_xor(partial, 2);
                partial += __shfl_xor(partial, 4);
                partial += __shfl_xor(partial, 8);
                if (rl == 0) atomicAdd(&rsum[row], partial);
            }
        }
    }
}

// ============================================================================
// small f32 weight-product GEMMs: 512x512x512, one launch for all three.
// op0: T0 = Wq1 @ Wk1^T ; op1: T1 = Wv1 @ Wo1 ; op2: T2 = Wq2 @ Wk2^T
// ============================================================================
__global__ __launch_bounds__(256) void wgemm3(
    const float* __restrict__ Wq1, const float* __restrict__ Wk1,
    const float* __restrict__ Wv1, const float* __restrict__ Wo1,
    const float* __restrict__ Wq2, const float* __restrict__ Wk2,
    float* __restrict__ T0, float* __restrict__ T1, float* __restrict__ T2)
{
    const int op = blockIdx.z;
    const float* A = (op == 0) ? Wq1 : (op == 1) ? Wv1 : Wq2;
    const float* B = (op == 0) ? Wk1 : (op == 1) ? Wo1 : Wk2;
    float* C = (op == 0) ? T0 : (op == 1) ? T1 : T2;
    const bool bt = (op != 1);

    __shared__ float As[32][65];
    __shared__ float Bs[32][65];
    const int tid = threadIdx.x;
    const int i0 = blockIdx.y * 64, j0 = blockIdx.x * 64;
    const int tx = tid & 15, ty = tid >> 4;
    float acc[4][4];
#pragma unroll
    for (int i = 0; i < 4; ++i)
#pragma unroll
        for (int j = 0; j < 4; ++j) acc[i][j] = 0.f;

    for (int k0 = 0; k0 < 512; k0 += 32) {
#pragma unroll
        for (int u = 0; u < 2; ++u) {
            int e = tid + u * 256;
            int r = e >> 3, c = (e & 7) * 4;
            float4 v = *(const float4*)(A + (long)(i0 + r) * 512 + k0 + c);
            As[c][r] = v.x; As[c + 1][r] = v.y; As[c + 2][r] = v.z; As[c + 3][r] = v.w;
        }
        if (bt) {
#pragma unroll
            for (int u = 0; u < 2; ++u) {
                int e = tid + u * 256;
                int r = e >> 3, c = (e & 7) * 4;
                float4 v = *(const float4*)(B + (long)(j0 + r) * 512 + k0 + c);
                Bs[c][r] = v.x; Bs[c + 1][r] = v.y; Bs[c + 2][r] = v.z; Bs[c + 3][r] = v.w;
            }
        } else {
#pragma unroll
            for (int u = 0; u < 2; ++u) {
                int e = tid + u * 256;
                int k = e >> 4, j = (e & 15) * 4;
                *(float4*)&Bs[k][j] = *(const float4*)(B + (long)(k0 + k) * 512 + j0 + j);
            }
        }
        __syncthreads();
#pragma unroll
        for (int kk = 0; kk < 32; ++kk) {
            float av[4], bv[4];
#pragma unroll
            for (int i = 0; i < 4; ++i) av[i] = As[kk][ty * 4 + i];
#pragma unroll
            for (int j = 0; j < 4; ++j) bv[j] = Bs[kk][tx * 4 + j];
#pragma unroll
            for (int i = 0; i < 4; ++i)
#pragma unroll
                for (int j = 0; j < 4; ++j)
                    acc[i][j] = fmaf(av[i], bv[j], acc[i][j]);
        }
        __syncthreads();
    }
#pragma unroll
    for (int i = 0; i < 4; ++i)
#pragma unroll
        for (int j = 0; j < 4; ++j)
            C[(long)(i0 + ty * 4 + i) * 512 + j0 + tx * 4 + j] = acc[i][j];
}

// ============================================================================
// helpers
// ============================================================================
__device__ __forceinline__ float waveReduceMax(float v) {
#pragma unroll
    for (int o = 32; o; o >>= 1) v = fmaxf(v, __shfl_down(v, o));
    return v;
}
__device__ __forceinline__ float waveReduceSum(float v) {
#pragma unroll
    for (int o = 32; o; o >>= 1) v += __shfl_down(v, o);
    return v;
}

// softmax over rows of 2048 f32 (in d_out); writes p1 hi/lo f16 IN PLACE:
// hi at f16-offset row*4096, lo at row*4096+2048.
__global__ __launch_bounds__(256) void softmax_split_kernel(float* __restrict__ S)
{
    __shared__ float red[4];
    __shared__ float fin;
    long row = blockIdx.x;
    float* p = S + row * (long)NN;
    half_t* ph = (half_t*)p;
    half_t* pl = ph + NN;
    int t = threadIdx.x;

    float4 v0 = *reinterpret_cast<float4*>(p + t * 8);
    float4 v1 = *reinterpret_cast<float4*>(p + t * 8 + 4);

    float m = fmaxf(fmaxf(fmaxf(v0.x, v0.y), fmaxf(v0.z, v0.w)),
                    fmaxf(fmaxf(v1.x, v1.y), fmaxf(v1.z, v1.w)));
    m = waveReduceMax(m);
    if ((t & 63) == 0) red[t >> 6] = m;
    __syncthreads();
    if (t == 0) fin = fmaxf(fmaxf(red[0], red[1]), fmaxf(red[2], red[3]));
    __syncthreads();
    m = fin;

    float e[8];
    e[0] = __expf(v0.x - m); e[1] = __expf(v0.y - m); e[2] = __expf(v0.z - m); e[3] = __expf(v0.w - m);
    e[4] = __expf(v1.x - m); e[5] = __expf(v1.y - m); e[6] = __expf(v1.z - m); e[7] = __expf(v1.w - m);
    float s = ((e[0] + e[1]) + (e[2] + e[3])) + ((e[4] + e[5]) + (e[6] + e[7]));
    s = waveReduceSum(s);
    __syncthreads();
    if ((t & 63) == 0) red[t >> 6] = s;
    __syncthreads();
    if (t == 0) fin = (red[0] + red[1]) + (red[2] + red[3]);
    __syncthreads();
    float inv = 1.0f / fin;

    __syncthreads();
    half8 hv, lv;
#pragma unroll
    for (int j = 0; j < 8; ++j) {
        float pv = e[j] * inv;
        half_t hh = (half_t)pv;
        hv[j] = hh;
        lv[j] = (half_t)(pv - (float)hh);
    }
    *(half8*)(ph + t * 8) = hv;
    *(half8*)(pl + t * 8) = lv;
}

// A = clip(surv / (sum+1e-9), 0, 1) in place, 8 floats/thread
__global__ __launch_bounds__(256) void norm_kernel(float* __restrict__ S, const float* __restrict__ sums)
{
    long i = (long)blockIdx.x * 256 + threadIdx.x;
    long base = i * 8;
    long row = base >> 11;   // NN = 2048
    float inv = 1.0f / (sums[row] + 1e-9f);
    float4 v0 = *reinterpret_cast<float4*>(S + base);
    float4 v1 = *reinterpret_cast<float4*>(S + base + 4);
    v0.x = fminf(v0.x * inv, 1.0f); v0.y = fminf(v0.y * inv, 1.0f);
    v0.z = fminf(v0.z * inv, 1.0f); v0.w = fminf(v0.w * inv, 1.0f);
    v1.x = fminf(v1.x * inv, 1.0f); v1.y = fminf(v1.y * inv, 1.0f);
    v1.z = fminf(v1.z * inv, 1.0f); v1.w = fminf(v1.w * inv, 1.0f);
    *reinterpret_cast<float4*>(S + base) = v0;
    *reinterpret_cast<float4*>(S + base + 4) = v1;
}

// thresh[i] = b2 ; sums[i] = 0
__global__ __launch_bounds__(256) void init_aux(float* __restrict__ thresh, float* __restrict__ sums,
                                                const float* __restrict__ b2)
{
    int i = blockIdx.x * 256 + threadIdx.x;
    if (i < MT) { thresh[i] = b2[0]; sums[i] = 0.f; }
}

// weight prep: W[K,N] f32 -> (mul*W)^T hi/lo f16 [N,K]
__global__ __launch_bounds__(256) void wprep(const float* __restrict__ W,
                                             half_t* __restrict__ Th, half_t* __restrict__ Tl,
                                             int K, int N, float mul)
{
    __shared__ float tw[32][33];
    int n0 = blockIdx.x * 32, k0 = blockIdx.y * 32;
    int c = threadIdx.x & 31, r8 = threadIdx.x >> 5;
#pragma unroll
    for (int i = 0; i < 4; ++i) {
        int r = r8 + i * 8;
        tw[r][c] = W[(long)(k0 + r) * N + n0 + c];
    }
    __syncthreads();
#pragma unroll
    for (int i = 0; i < 4; ++i) {
        int nr = r8 + i * 8;
        float v = tw[c][nr] * mul;
        half_t hh = (half_t)v;
        Th[(long)(n0 + nr) * K + k0 + c] = hh;
        Tl[(long)(n0 + nr) * K + k0 + c] = (half_t)(v - (float)hh);
    }
}

// X f32 -> hi/lo f16 (no transpose)
__global__ __launch_bounds__(256) void split_f32(const float* __restrict__ in,
                                                 half_t* __restrict__ hi, half_t* __restrict__ lo)
{
    long i = ((long)blockIdx.x * 256 + threadIdx.x) * 8;
    float4 a = *(const float4*)(in + i), b = *(const float4*)(in + i + 4);
    float v[8] = {a.x, a.y, a.z, a.w, b.x, b.y, b.z, b.w};
    half8 hv, lv;
#pragma unroll
    for (int j = 0; j < 8; ++j) {
        half_t hh = (half_t)v[j];
        hv[j] = hh;
        lv[j] = (half_t)(v[j] - (float)hh);
    }
    *(half8*)(hi + i) = hv;
    *(half8*)(lo + i) = lv;
}

// ============================================================================
// host-side dispatch
// ============================================================================
static void launch_gemm16(hipStream_t s, int epi,
    const half_t* Ahi, const half_t* Alo, long lda, long sA,
    const half_t* Bhi, const half_t* Blo, long ldb, long sB,
    float* Cf, half_t* Chi, half_t* Clo, long ldc, long sC, long slotS,
    int M, int N, int K, int batch, float alpha,
    const float* bias, const float* tvec, float* rsum)
{
    dim3 g(N / 128, M / 128, batch), b(256, 1, 1);
    if (epi == 0)      gemm_f16s<0><<<g, b, 0, s>>>(Ahi, Alo, lda, sA, Bhi, Blo, ldb, sB, Cf, Chi, Clo, ldc, sC, slotS, K, alpha, bias, tvec, rsum);
    else if (epi == 1) gemm_f16s<1><<<g, b, 0, s>>>(Ahi, Alo, lda, sA, Bhi, Blo, ldb, sB, Cf, Chi, Clo, ldc, sC, slotS, K, alpha, bias, tvec, rsum);
    else if (epi == 3) gemm_f16s<3><<<g, b, 0, s>>>(Ahi, Alo, lda, sA, Bhi, Blo, ldb, sB, Cf, Chi, Clo, ldc, sC, slotS, K, alpha, bias, tvec, rsum);
    else               gemm_f16s<4><<<g, b, 0, s>>>(Ahi, Alo, lda, sA, Bhi, Blo, ldb, sB, Cf, Chi, Clo, ldc, sC, slotS, K, alpha, bias, tvec, rsum);
}

extern "C" void kernel_launch(void* const* d_in, const int* in_sizes, int n_in,
                              void* d_out, int out_size, void* d_ws, size_t ws_size,
                              hipStream_t stream)
{
    const float* X   = (const float*)d_in[0];
    const float* Wq1 = (const float*)d_in[1];
    const float* Wk1 = (const float*)d_in[2];
    const float* Wv1 = (const float*)d_in[3];
    const float* Wo1 = (const float*)d_in[4];
    const float* Wq2 = (const float*)d_in[5];
    const float* Wk2 = (const float*)d_in[6];
    const float* W1  = (const float*)d_in[7];
    const float* b1  = (const float*)d_in[8];
    const float* W2  = (const float*)d_in[9];
    const float* b2  = (const float*)d_in[10];

    float* out = (float*)d_out;
    const float scale = 0.044194173824159216f;   // 1/sqrt(512)
    const float WM = 8.0f, WMI = 0.125f;         // weight-product pre-split rescale

    // ---- workspace layout ----
    half_t* wsH = (half_t*)d_ws;
    const long U  = (long)MT * DD;               // 8,388,608
    const long WD = (long)DD * DD;               // 262,144
    half_t* sXh = wsH;          half_t* sXl = wsH + U;        // slot A: X
    half_t* sBh = wsH + 2 * U;  half_t* sBl = wsH + 3 * U;    // slot B: y1 -> voT -> y2
    half_t* sCh = wsH + 4 * U;  half_t* sCl = wsH + 5 * U;    // slot C: att
    half_t* wptr = wsH + 6 * U;
    half_t* mb1h = wptr;            half_t* mb1l = mb1h + WD;  // (Wq1 Wk1^T)^T split
    half_t* mvoh = mb1l + WD;       half_t* mvol = mvoh + WD;  // (Wv1 Wo1)^T split
    half_t* mb2h = mvol + WD;       half_t* mb2l = mb2h + WD;  // (Wq2 Wk2^T)^T split
    half_t* w1h  = mb2l + WD;       half_t* w1l  = w1h + (long)DD * CFF;
    float*  T0 = (float*)(w1l + (long)DD * CFF);
    float*  T1 = T0 + WD;
    float*  T2 = T1 + WD;
    float*  thresh = T2 + WD;
    float*  sums   = thresh + MT;

    // ---- prep ----
    init_aux<<<dim3(64), dim3(256), 0, stream>>>(thresh, sums, b2);
    split_f32<<<dim3(4096), dim3(256), 0, stream>>>(X, sXh, sXl);
    wgemm3<<<dim3(8, 8, 3), dim3(256), 0, stream>>>(Wq1, Wk1, Wv1, Wo1, Wq2, Wk2, T0, T1, T2);
    wprep<<<dim3(16, 16), dim3(256), 0, stream>>>(T0, mb1h, mb1l, DD, DD, WM);
    wprep<<<dim3(16, 16), dim3(256), 0, stream>>>(T1, mvoh, mvol, DD, DD, WM);
    wprep<<<dim3(16, 16), dim3(256), 0, stream>>>(T2, mb2h, mb2l, DD, DD, WM);
    wprep<<<dim3(4, 16),  dim3(256), 0, stream>>>(W1, w1h, w1l, DD, CFF, 1.0f);

    // 1) y1 = X @ (Wq1 Wk1^T)  -> slot B  (EPI=1, alpha undoes WM)
    launch_gemm16(stream, 1, sXh, sXl, DD, 0, mb1h, mb1l, DD, 0,
                  nullptr, sBh, sBl, DD, 0, 0, MT, DD, DD, 1, WMI, nullptr, nullptr, nullptr);

    // 2) s1 = scale * y1 @ X^T (batched) -> d_out f32
    launch_gemm16(stream, 0, sBh, sBl, DD, (long)NN * DD, sXh, sXl, DD, (long)NN * DD,
                  out, nullptr, nullptr, NN, (long)NN * NN, 0, NN, NN, DD, BB, scale, nullptr, nullptr, nullptr);

    // 3) voT = (Wv1 Wo1)^T @ X^T (batched) -> slot B [8][512][2048] (y1 dead)
    //    slotS=512 + ldc=2048 makes the col>>9 slot logic the identity.
    launch_gemm16(stream, 1, mvoh, mvol, DD, 0, sXh, sXl, DD, (long)NN * DD,
                  nullptr, sBh, sBl, NN, (long)DD * NN, 512, DD, NN, DD, BB, WMI, nullptr, nullptr, nullptr);

    // 4) softmax(s1) -> p1 hi/lo f16 in place in d_out
    softmax_split_kernel<<<dim3(MT), dim3(256), 0, stream>>>(out);

    // 5) att = p1 @ vo (batched) -> slot C  (X dead after voT; p1 consumed here)
    {
        const half_t* p1h = (const half_t*)d_out;
        const half_t* p1l = p1h + NN;
        launch_gemm16(stream, 1, p1h, p1l, 2 * NN, (long)NN * 2 * NN,
                      sBh, sBl, NN, (long)DD * NN,
                      nullptr, sCh, sCl, DD, (long)NN * DD, 0, NN, DD, NN, BB, 1.f, nullptr, nullptr, nullptr);
    }

    // 6) y2 = att @ (Wq2 Wk2^T) -> slot B (voT dead)
    launch_gemm16(stream, 1, sCh, sCl, DD, 0, mb2h, mb2l, DD, 0,
                  nullptr, sBh, sBl, DD, 0, 0, MT, DD, DD, 1, WMI, nullptr, nullptr, nullptr);

    // 7) fused h+thresh: thresh += leakyrelu(att@W1 + b1) @ W2
    launch_gemm16(stream, 4, sCh, sCl, DD, 0, w1h, w1l, DD, 0,
                  nullptr, nullptr, nullptr, CFF, 0, 0, MT, CFF, DD, 1, 1.f, b1, W2, thresh);

    // 8) surv = max(scale * y2 @ att^T - thresh, 0) -> d_out, + atomic row sums
    launch_gemm16(stream, 3, sBh, sBl, DD, (long)NN * DD, sCh, sCl, DD, (long)NN * DD,
                  out, nullptr, nullptr, NN, (long)NN * NN, 0, NN, NN, DD, BB, scale, nullptr, thresh, sums);

    // 9) A = clip(surv/(sum+1e-9), 0, 1)
    norm_kernel<<<dim3(out_size / 2048), dim3(256), 0, stream>>>(out, sums);
}

// Round 5
// 728.052 us; speedup vs baseline: 2.8703x; 1.0461x over previous
//
#include <hip/hip_runtime.h>
#include <hip/hip_bf16.h>

// Problem constants
#define BB 8
#define NN 2048
#define DD 512
#define CFF 128
#define MT (BB*NN)   // 16384

typedef _Float16 half_t;
typedef __attribute__((ext_vector_type(8))) _Float16 half8;
typedef __attribute__((ext_vector_type(4))) float floatx4;
typedef __attribute__((ext_vector_type(4))) unsigned int uint4v;

#define MFMA16(a,b,c) __builtin_amdgcn_mfma_f32_16x16x32_f16((a),(b),(c),0,0,0)

// ============================================================================
// fp16-split MFMA GEMM:  C = epi( alpha * (Ahi+Alo) @ (Bhi+Blo)^T )
// A: [M,K] row-major (lda), B: [N,K] row-major (ldb), hi/lo f16 pre-split.
// 3-pass Markidis: hi*hi + lo*hi + hi*lo. Tile 128x128, BK=32, 4 waves 64x64.
// T1 XCD-chunked tile swizzle. Schedule per K-step:
//   barrier -> issue next-tile global loads -> ds_read cur -> setprio(1)
//   48 MFMA -> setprio(0) -> write_lds(next)  [vmcnt wait lands here, hidden]
// LDS swizzle: chunk = kc ^ ((row>>1)&3)  -> 2-way max on read AND write (free).
// EPI: 0 = alpha*acc -> Cf
//      1 = alpha*acc, hi/lo split -> Chi/Clo (col>>9 slot logic)
//      3 = max(alpha*acc - tvec[z*NN+row],0) -> Cf, + atomicAdd row sums
//      4 = leakyrelu(acc+bias[col]) . tvec(=W2) -> atomicAdd rsum(=thresh)
// ============================================================================
template<int EPI>
__global__ __launch_bounds__(256) void gemm_f16s(
    const half_t* __restrict__ Ahi, const half_t* __restrict__ Alo, long lda, long sA,
    const half_t* __restrict__ Bhi, const half_t* __restrict__ Blo, long ldb, long sB,
    float* __restrict__ Cf, half_t* __restrict__ Chi, half_t* __restrict__ Clo,
    long ldc, long sC, long slotS,
    int K, float alpha, const float* __restrict__ bias, const float* __restrict__ tvec,
    float* __restrict__ rsum)
{
    // ---- XCD-chunked swizzle (all grids have total % 8 == 0) ----
    const int gx = gridDim.x, gy = gridDim.y;
    int d = blockIdx.x + gx * (blockIdx.y + gy * blockIdx.z);
    int total = gx * gy * gridDim.z;
    int t0 = (d & 7) * (total >> 3) + (d >> 3);
    int bx = t0 % gx;
    int t1 = t0 / gx;
    int by = t1 % gy;
    int bz = t1 / gy;

    const int tid = threadIdx.x;
    const int row0 = by * 128, col0 = bx * 128;
    const long z = bz;
    const half_t* pAh = Ahi + z * sA + (long)row0 * lda;
    const half_t* pAl = Alo + z * sA + (long)row0 * lda;
    const half_t* pBh = Bhi + z * sB + (long)col0 * ldb;
    const half_t* pBl = Blo + z * sB + (long)col0 * ldb;

    __shared__ half_t lds[2][4][4096];   // [buf][Ah,Al,Bh,Bl][128*32]

    const int l  = tid & 63;
    const int w  = tid >> 6;
    const int wr = w >> 1, wc = w & 1;
    const int Rw = wr * 64, Cw = wc * 64;
    const int rl = l & 15, kc = l >> 4;            // frag row/col, k-chunk
    const int swz = (kc ^ ((rl >> 1) & 3)) * 8;    // 2-way-max swizzled k-offset

    floatx4 acc[4][4];
#pragma unroll
    for (int m = 0; m < 4; ++m)
#pragma unroll
        for (int n = 0; n < 4; ++n) acc[m][n] = (floatx4){0.f, 0.f, 0.f, 0.f};

    const int r0s = tid >> 2,         c0s = tid & 3;
    const int r1s = (tid + 256) >> 2, c1s = tid & 3;
    const int off0 = r0s * 32 + ((c0s ^ ((r0s >> 1) & 3)) * 8);
    const int off1 = r1s * 32 + ((c1s ^ ((r1s >> 1) & 3)) * 8);

    auto load_regs = [&](int k0, uint4v* r) {
        long ga0 = (long)r0s * lda + k0 + c0s * 8;
        long gb0 = (long)r0s * ldb + k0 + c0s * 8;
        long ga1 = (long)r1s * lda + k0 + c1s * 8;
        long gb1 = (long)r1s * ldb + k0 + c1s * 8;
        r[0] = *(const uint4v*)(pAh + ga0);
        r[1] = *(const uint4v*)(pAl + ga0);
        r[2] = *(const uint4v*)(pBh + gb0);
        r[3] = *(const uint4v*)(pBl + gb0);
        r[4] = *(const uint4v*)(pAh + ga1);
        r[5] = *(const uint4v*)(pAl + ga1);
        r[6] = *(const uint4v*)(pBh + gb1);
        r[7] = *(const uint4v*)(pBl + gb1);
    };
    auto write_lds = [&](int buf, const uint4v* r) {
        *(uint4v*)&lds[buf][0][off0] = r[0];
        *(uint4v*)&lds[buf][1][off0] = r[1];
        *(uint4v*)&lds[buf][2][off0] = r[2];
        *(uint4v*)&lds[buf][3][off0] = r[3];
        *(uint4v*)&lds[buf][0][off1] = r[4];
        *(uint4v*)&lds[buf][1][off1] = r[5];
        *(uint4v*)&lds[buf][2][off1] = r[6];
        *(uint4v*)&lds[buf][3][off1] = r[7];
    };

    const int nk = K >> 5;
    uint4v rg[8];
    load_regs(0, rg);
    write_lds(0, rg);
#pragma unroll 2
    for (int t = 0; t < nk; ++t) {
        __syncthreads();                               // buf[t&1] ready for all
        if (t + 1 < nk) load_regs((t + 1) << 5, rg);   // issue AFTER barrier: flies under MFMAs
        const int cur = t & 1;
        const half_t* bAh = &lds[cur][0][0];
        const half_t* bAl = &lds[cur][1][0];
        const half_t* bBh = &lds[cur][2][0];
        const half_t* bBl = &lds[cur][3][0];
        half8 af[4][2], bf[4][2];
#pragma unroll
        for (int m = 0; m < 4; ++m) {
            int off = (Rw + m * 16 + rl) * 32 + swz;
            af[m][0] = *(const half8*)(bAh + off);
            af[m][1] = *(const half8*)(bAl + off);
        }
#pragma unroll
        for (int n = 0; n < 4; ++n) {
            int off = (Cw + n * 16 + rl) * 32 + swz;
            bf[n][0] = *(const half8*)(bBh + off);
            bf[n][1] = *(const half8*)(bBl + off);
        }
        __builtin_amdgcn_s_setprio(1);
#pragma unroll
        for (int m = 0; m < 4; ++m)
#pragma unroll
            for (int n = 0; n < 4; ++n) {
                acc[m][n] = MFMA16(af[m][0], bf[n][0], acc[m][n]);
                acc[m][n] = MFMA16(af[m][1], bf[n][0], acc[m][n]);
                acc[m][n] = MFMA16(af[m][0], bf[n][1], acc[m][n]);
            }
        __builtin_amdgcn_s_setprio(0);
        if (t + 1 < nk) write_lds((t + 1) & 1, rg);    // vmcnt wait here (latency hidden)
    }

    // ---- epilogue — C/D frag: col = lane&15, row = (lane>>4)*4 + reg ----
    if (EPI == 0) {
#pragma unroll
        for (int m = 0; m < 4; ++m)
#pragma unroll
            for (int n = 0; n < 4; ++n) {
                int col = col0 + Cw + n * 16 + rl;
#pragma unroll
                for (int r = 0; r < 4; ++r) {
                    int row = row0 + Rw + m * 16 + kc * 4 + r;
                    Cf[z * sC + (long)row * ldc + col] = acc[m][n][r] * alpha;
                }
            }
    } else if (EPI == 1) {
#pragma unroll
        for (int m = 0; m < 4; ++m)
#pragma unroll
            for (int n = 0; n < 4; ++n) {
                int col = col0 + Cw + n * 16 + rl;
                long obase = (long)(col >> 9) * slotS + z * sC + (col & 511);
#pragma unroll
                for (int r = 0; r < 4; ++r) {
                    int row = row0 + Rw + m * 16 + kc * 4 + r;
                    long o = obase + (long)row * ldc;
                    float v = acc[m][n][r] * alpha;
                    half_t hh = (half_t)v;
                    Chi[o] = hh;
                    Clo[o] = (half_t)(v - (float)hh);
                }
            }
    } else if (EPI == 3) {
        const float* tv = tvec + z * NN;
        float* rs = rsum + z * NN;
#pragma unroll
        for (int m = 0; m < 4; ++m) {
#pragma unroll
            for (int r = 0; r < 4; ++r) {
                int row = row0 + Rw + m * 16 + kc * 4 + r;
                float tvr = tv[row];
                float partial = 0.f;
#pragma unroll
                for (int n = 0; n < 4; ++n) {
                    int col = col0 + Cw + n * 16 + rl;
                    float v = fmaxf(acc[m][n][r] * alpha - tvr, 0.f);
                    Cf[z * sC + (long)row * ldc + col] = v;
                    partial += v;
                }
                partial += __shfl_xor(partial, 1);
                partial += __shfl_xor(partial, 2);
                partial += __shfl_xor(partial, 4);
                partial += __shfl_xor(partial, 8);
                if (rl == 0) atomicAdd(&rs[row], partial);
            }
        }
    } else {  // EPI == 4: fused h + thresh (bias=b1, tvec=W2, rsum=thresh)
        float w2v[4], bv[4];
#pragma unroll
        for (int n = 0; n < 4; ++n) {
            int col = Cw + n * 16 + rl;
            bv[n]  = bias[col];
            w2v[n] = tvec[col];
        }
#pragma unroll
        for (int m = 0; m < 4; ++m) {
#pragma unroll
            for (int r = 0; r < 4; ++r) {
                int row = row0 + Rw + m * 16 + kc * 4 + r;
                float partial = 0.f;
#pragma unroll
                for (int n = 0; n < 4; ++n) {
                    float v = acc[m][n][r] + bv[n];
                    v = (v >= 0.f) ? v : 0.1f * v;
                    partial += v * w2v[n];
                }
                partial += __shfl_xor(partial, 1);
                partial += __shfl_xor(partial, 2);
                partial += __shfl_xor(partial, 4);
                partial += __shfl_xor(partial, 8);
                if (rl == 0) atomicAdd(&rsum[row], partial);
            }
        }
    }
}

// ============================================================================
// small f32 weight-product GEMMs: 512x512x512, one launch for all three.
// op0: T0 = Wq1 @ Wk1^T ; op1: T1 = Wv1 @ Wo1 ; op2: T2 = Wq2 @ Wk2^T
// ============================================================================
__global__ __launch_bounds__(256) void wgemm3(
    const float* __restrict__ Wq1, const float* __restrict__ Wk1,
    const float* __restrict__ Wv1, const float* __restrict__ Wo1,
    const float* __restrict__ Wq2, const float* __restrict__ Wk2,
    float* __restrict__ T0, float* __restrict__ T1, float* __restrict__ T2)
{
    const int op = blockIdx.z;
    const float* A = (op == 0) ? Wq1 : (op == 1) ? Wv1 : Wq2;
    const float* B = (op == 0) ? Wk1 : (op == 1) ? Wo1 : Wk2;
    float* C = (op == 0) ? T0 : (op == 1) ? T1 : T2;
    const bool bt = (op != 1);

    __shared__ float As[32][65];
    __shared__ float Bs[32][65];
    const int tid = threadIdx.x;
    const int i0 = blockIdx.y * 64, j0 = blockIdx.x * 64;
    const int tx = tid & 15, ty = tid >> 4;
    float acc[4][4];
#pragma unroll
    for (int i = 0; i < 4; ++i)
#pragma unroll
        for (int j = 0; j < 4; ++j) acc[i][j] = 0.f;

    for (int k0 = 0; k0 < 512; k0 += 32) {
#pragma unroll
        for (int u = 0; u < 2; ++u) {
            int e = tid + u * 256;
            int r = e >> 3, c = (e & 7) * 4;
            float4 v = *(const float4*)(A + (long)(i0 + r) * 512 + k0 + c);
            As[c][r] = v.x; As[c + 1][r] = v.y; As[c + 2][r] = v.z; As[c + 3][r] = v.w;
        }
        if (bt) {
#pragma unroll
            for (int u = 0; u < 2; ++u) {
                int e = tid + u * 256;
                int r = e >> 3, c = (e & 7) * 4;
                float4 v = *(const float4*)(B + (long)(j0 + r) * 512 + k0 + c);
                Bs[c][r] = v.x; Bs[c + 1][r] = v.y; Bs[c + 2][r] = v.z; Bs[c + 3][r] = v.w;
            }
        } else {
#pragma unroll
            for (int u = 0; u < 2; ++u) {
                int e = tid + u * 256;
                int k = e >> 4, j = (e & 15) * 4;
                *(float4*)&Bs[k][j] = *(const float4*)(B + (long)(k0 + k) * 512 + j0 + j);
            }
        }
        __syncthreads();
#pragma unroll
        for (int kk = 0; kk < 32; ++kk) {
            float av[4], bv[4];
#pragma unroll
            for (int i = 0; i < 4; ++i) av[i] = As[kk][ty * 4 + i];
#pragma unroll
            for (int j = 0; j < 4; ++j) bv[j] = Bs[kk][tx * 4 + j];
#pragma unroll
            for (int i = 0; i < 4; ++i)
#pragma unroll
                for (int j = 0; j < 4; ++j)
                    acc[i][j] = fmaf(av[i], bv[j], acc[i][j]);
        }
        __syncthreads();
    }
#pragma unroll
    for (int i = 0; i < 4; ++i)
#pragma unroll
        for (int j = 0; j < 4; ++j)
            C[(long)(i0 + ty * 4 + i) * 512 + j0 + tx * 4 + j] = acc[i][j];
}

// ============================================================================
// helpers
// ============================================================================
__device__ __forceinline__ float waveReduceMax(float v) {
#pragma unroll
    for (int o = 32; o; o >>= 1) v = fmaxf(v, __shfl_down(v, o));
    return v;
}
__device__ __forceinline__ float waveReduceSum(float v) {
#pragma unroll
    for (int o = 32; o; o >>= 1) v += __shfl_down(v, o);
    return v;
}

// softmax over rows of 2048 f32 (in d_out); writes p1 hi/lo f16 IN PLACE:
// hi at f16-offset row*4096, lo at row*4096+2048.
__global__ __launch_bounds__(256) void softmax_split_kernel(float* __restrict__ S)
{
    __shared__ float red[4];
    __shared__ float fin;
    long row = blockIdx.x;
    float* p = S + row * (long)NN;
    half_t* ph = (half_t*)p;
    half_t* pl = ph + NN;
    int t = threadIdx.x;

    float4 v0 = *reinterpret_cast<float4*>(p + t * 8);
    float4 v1 = *reinterpret_cast<float4*>(p + t * 8 + 4);

    float m = fmaxf(fmaxf(fmaxf(v0.x, v0.y), fmaxf(v0.z, v0.w)),
                    fmaxf(fmaxf(v1.x, v1.y), fmaxf(v1.z, v1.w)));
    m = waveReduceMax(m);
    if ((t & 63) == 0) red[t >> 6] = m;
    __syncthreads();
    if (t == 0) fin = fmaxf(fmaxf(red[0], red[1]), fmaxf(red[2], red[3]));
    __syncthreads();
    m = fin;

    float e[8];
    e[0] = __expf(v0.x - m); e[1] = __expf(v0.y - m); e[2] = __expf(v0.z - m); e[3] = __expf(v0.w - m);
    e[4] = __expf(v1.x - m); e[5] = __expf(v1.y - m); e[6] = __expf(v1.z - m); e[7] = __expf(v1.w - m);
    float s = ((e[0] + e[1]) + (e[2] + e[3])) + ((e[4] + e[5]) + (e[6] + e[7]));
    s = waveReduceSum(s);
    __syncthreads();
    if ((t & 63) == 0) red[t >> 6] = s;
    __syncthreads();
    if (t == 0) fin = (red[0] + red[1]) + (red[2] + red[3]);
    __syncthreads();
    float inv = 1.0f / fin;

    __syncthreads();
    half8 hv, lv;
#pragma unroll
    for (int j = 0; j < 8; ++j) {
        float pv = e[j] * inv;
        half_t hh = (half_t)pv;
        hv[j] = hh;
        lv[j] = (half_t)(pv - (float)hh);
    }
    *(half8*)(ph + t * 8) = hv;
    *(half8*)(pl + t * 8) = lv;
}

// A = clip(surv / (sum+1e-9), 0, 1) in place, 8 floats/thread
__global__ __launch_bounds__(256) void norm_kernel(float* __restrict__ S, const float* __restrict__ sums)
{
    long i = (long)blockIdx.x * 256 + threadIdx.x;
    long base = i * 8;
    long row = base >> 11;   // NN = 2048
    float inv = 1.0f / (sums[row] + 1e-9f);
    float4 v0 = *reinterpret_cast<float4*>(S + base);
    float4 v1 = *reinterpret_cast<float4*>(S + base + 4);
    v0.x = fminf(v0.x * inv, 1.0f); v0.y = fminf(v0.y * inv, 1.0f);
    v0.z = fminf(v0.z * inv, 1.0f); v0.w = fminf(v0.w * inv, 1.0f);
    v1.x = fminf(v1.x * inv, 1.0f); v1.y = fminf(v1.y * inv, 1.0f);
    v1.z = fminf(v1.z * inv, 1.0f); v1.w = fminf(v1.w * inv, 1.0f);
    *reinterpret_cast<float4*>(S + base) = v0;
    *reinterpret_cast<float4*>(S + base + 4) = v1;
}

// thresh[i] = b2 ; sums[i] = 0
__global__ __launch_bounds__(256) void init_aux(float* __restrict__ thresh, float* __restrict__ sums,
                                                const float* __restrict__ b2)
{
    int i = blockIdx.x * 256 + threadIdx.x;
    if (i < MT) { thresh[i] = b2[0]; sums[i] = 0.f; }
}

// weight prep: W[K,N] f32 -> (mul*W)^T hi/lo f16 [N,K]
__global__ __launch_bounds__(256) void wprep(const float* __restrict__ W,
                                             half_t* __restrict__ Th, half_t* __restrict__ Tl,
                                             int K, int N, float mul)
{
    __shared__ float tw[32][33];
    int n0 = blockIdx.x * 32, k0 = blockIdx.y * 32;
    int c = threadIdx.x & 31, r8 = threadIdx.x >> 5;
#pragma unroll
    for (int i = 0; i < 4; ++i) {
        int r = r8 + i * 8;
        tw[r][c] = W[(long)(k0 + r) * N + n0 + c];
    }
    __syncthreads();
#pragma unroll
    for (int i = 0; i < 4; ++i) {
        int nr = r8 + i * 8;
        float v = tw[c][nr] * mul;
        half_t hh = (half_t)v;
        Th[(long)(n0 + nr) * K + k0 + c] = hh;
        Tl[(long)(n0 + nr) * K + k0 + c] = (half_t)(v - (float)hh);
    }
}

// X f32 -> hi/lo f16 (no transpose)
__global__ __launch_bounds__(256) void split_f32(const float* __restrict__ in,
                                                 half_t* __restrict__ hi, half_t* __restrict__ lo)
{
    long i = ((long)blockIdx.x * 256 + threadIdx.x) * 8;
    float4 a = *(const float4*)(in + i), b = *(const float4*)(in + i + 4);
    float v[8] = {a.x, a.y, a.z, a.w, b.x, b.y, b.z, b.w};
    half8 hv, lv;
#pragma unroll
    for (int j = 0; j < 8; ++j) {
        half_t hh = (half_t)v[j];
        hv[j] = hh;
        lv[j] = (half_t)(v[j] - (float)hh);
    }
    *(half8*)(hi + i) = hv;
    *(half8*)(lo + i) = lv;
}

// ============================================================================
// host-side dispatch
// ============================================================================
static void launch_gemm16(hipStream_t s, int epi,
    const half_t* Ahi, const half_t* Alo, long lda, long sA,
    const half_t* Bhi, const half_t* Blo, long ldb, long sB,
    float* Cf, half_t* Chi, half_t* Clo, long ldc, long sC, long slotS,
    int M, int N, int K, int batch, float alpha,
    const float* bias, const float* tvec, float* rsum)
{
    dim3 g(N / 128, M / 128, batch), b(256, 1, 1);
    if (epi == 0)      gemm_f16s<0><<<g, b, 0, s>>>(Ahi, Alo, lda, sA, Bhi, Blo, ldb, sB, Cf, Chi, Clo, ldc, sC, slotS, K, alpha, bias, tvec, rsum);
    else if (epi == 1) gemm_f16s<1><<<g, b, 0, s>>>(Ahi, Alo, lda, sA, Bhi, Blo, ldb, sB, Cf, Chi, Clo, ldc, sC, slotS, K, alpha, bias, tvec, rsum);
    else if (epi == 3) gemm_f16s<3><<<g, b, 0, s>>>(Ahi, Alo, lda, sA, Bhi, Blo, ldb, sB, Cf, Chi, Clo, ldc, sC, slotS, K, alpha, bias, tvec, rsum);
    else               gemm_f16s<4><<<g, b, 0, s>>>(Ahi, Alo, lda, sA, Bhi, Blo, ldb, sB, Cf, Chi, Clo, ldc, sC, slotS, K, alpha, bias, tvec, rsum);
}

extern "C" void kernel_launch(void* const* d_in, const int* in_sizes, int n_in,
                              void* d_out, int out_size, void* d_ws, size_t ws_size,
                              hipStream_t stream)
{
    const float* X   = (const float*)d_in[0];
    const float* Wq1 = (const float*)d_in[1];
    const float* Wk1 = (const float*)d_in[2];
    const float* Wv1 = (const float*)d_in[3];
    const float* Wo1 = (const float*)d_in[4];
    const float* Wq2 = (const float*)d_in[5];
    const float* Wk2 = (const float*)d_in[6];
    const float* W1  = (const float*)d_in[7];
    const float* b1  = (const float*)d_in[8];
    const float* W2  = (const float*)d_in[9];
    const float* b2  = (const float*)d_in[10];

    float* out = (float*)d_out;
    const float scale = 0.044194173824159216f;   // 1/sqrt(512)
    const float WM = 8.0f, WMI = 0.125f;         // weight-product pre-split rescale

    // ---- workspace layout ----
    half_t* wsH = (half_t*)d_ws;
    const long U  = (long)MT * DD;               // 8,388,608
    const long WD = (long)DD * DD;               // 262,144
    half_t* sXh = wsH;          half_t* sXl = wsH + U;        // slot A: X
    half_t* sBh = wsH + 2 * U;  half_t* sBl = wsH + 3 * U;    // slot B: y1 -> voT -> y2
    half_t* sCh = wsH + 4 * U;  half_t* sCl = wsH + 5 * U;    // slot C: att
    half_t* wptr = wsH + 6 * U;
    half_t* mb1h = wptr;            half_t* mb1l = mb1h + WD;  // (Wq1 Wk1^T)^T split
    half_t* mvoh = mb1l + WD;       half_t* mvol = mvoh + WD;  // (Wv1 Wo1)^T split
    half_t* mb2h = mvol + WD;       half_t* mb2l = mb2h + WD;  // (Wq2 Wk2^T)^T split
    half_t* w1h  = mb2l + WD;       half_t* w1l  = w1h + (long)DD * CFF;
    float*  T0 = (float*)(w1l + (long)DD * CFF);
    float*  T1 = T0 + WD;
    float*  T2 = T1 + WD;
    float*  thresh = T2 + WD;
    float*  sums   = thresh + MT;

    // ---- prep ----
    init_aux<<<dim3(64), dim3(256), 0, stream>>>(thresh, sums, b2);
    split_f32<<<dim3(4096), dim3(256), 0, stream>>>(X, sXh, sXl);
    wgemm3<<<dim3(8, 8, 3), dim3(256), 0, stream>>>(Wq1, Wk1, Wv1, Wo1, Wq2, Wk2, T0, T1, T2);
    wprep<<<dim3(16, 16), dim3(256), 0, stream>>>(T0, mb1h, mb1l, DD, DD, WM);
    wprep<<<dim3(16, 16), dim3(256), 0, stream>>>(T1, mvoh, mvol, DD, DD, WM);
    wprep<<<dim3(16, 16), dim3(256), 0, stream>>>(T2, mb2h, mb2l, DD, DD, WM);
    wprep<<<dim3(4, 16),  dim3(256), 0, stream>>>(W1, w1h, w1l, DD, CFF, 1.0f);

    // 1) y1 = X @ (Wq1 Wk1^T)  -> slot B  (EPI=1, alpha undoes WM)
    launch_gemm16(stream, 1, sXh, sXl, DD, 0, mb1h, mb1l, DD, 0,
                  nullptr, sBh, sBl, DD, 0, 0, MT, DD, DD, 1, WMI, nullptr, nullptr, nullptr);

    // 2) s1 = scale * y1 @ X^T (batched) -> d_out f32
    launch_gemm16(stream, 0, sBh, sBl, DD, (long)NN * DD, sXh, sXl, DD, (long)NN * DD,
                  out, nullptr, nullptr, NN, (long)NN * NN, 0, NN, NN, DD, BB, scale, nullptr, nullptr, nullptr);

    // 3) voT = (Wv1 Wo1)^T @ X^T (batched) -> slot B [8][512][2048] (y1 dead)
    launch_gemm16(stream, 1, mvoh, mvol, DD, 0, sXh, sXl, DD, (long)NN * DD,
                  nullptr, sBh, sBl, NN, (long)DD * NN, 512, DD, NN, DD, BB, WMI, nullptr, nullptr, nullptr);

    // 4) softmax(s1) -> p1 hi/lo f16 in place in d_out
    softmax_split_kernel<<<dim3(MT), dim3(256), 0, stream>>>(out);

    // 5) att = p1 @ vo (batched) -> slot C  (X dead after voT; p1 consumed here)
    {
        const half_t* p1h = (const half_t*)d_out;
        const half_t* p1l = p1h + NN;
        launch_gemm16(stream, 1, p1h, p1l, 2 * NN, (long)NN * 2 * NN,
                      sBh, sBl, NN, (long)DD * NN,
                      nullptr, sCh, sCl, DD, (long)NN * DD, 0, NN, DD, NN, BB, 1.f, nullptr, nullptr, nullptr);
    }

    // 6) y2 = att @ (Wq2 Wk2^T) -> slot B (voT dead)
    launch_gemm16(stream, 1, sCh, sCl, DD, 0, mb2h, mb2l, DD, 0,
                  nullptr, sBh, sBl, DD, 0, 0, MT, DD, DD, 1, WMI, nullptr, nullptr, nullptr);

    // 7) fused h+thresh: thresh += leakyrelu(att@W1 + b1) @ W2
    launch_gemm16(stream, 4, sCh, sCl, DD, 0, w1h, w1l, DD, 0,
                  nullptr, nullptr, nullptr, CFF, 0, 0, MT, CFF, DD, 1, 1.f, b1, W2, thresh);

    // 8) surv = max(scale * y2 @ att^T - thresh, 0) -> d_out, + atomic row sums
    launch_gemm16(stream, 3, sBh, sBl, DD, (long)NN * DD, sCh, sCl, DD, (long)NN * DD,
                  out, nullptr, nullptr, NN, (long)NN * NN, 0, NN, NN, DD, BB, scale, nullptr, thresh, sums);

    // 9) A = clip(surv/(sum+1e-9), 0, 1)
    norm_kernel<<<dim3(out_size / 2048), dim3(256), 0, stream>>>(out, sums);
}